// Round 1
// baseline (1564.470 us; speedup 1.0000x reference)
//
#include <hip/hip_runtime.h>
#include <hip/hip_bf16.h>

#define NN 100000      // nodes
#define FIN 256        // input features
#define FH 64          // hidden features
#define NEG 0.01f

// ---------------------------------------------------------------------------
// ws layout (floats): h[NN*FH] | ne[NN*FH] | deg[NN] | flag(int)
// ---------------------------------------------------------------------------

// Detect whether index buffers are int64 (hi words zero) or int32.
__global__ void detect_kernel(const int* __restrict__ ei32, int* __restrict__ flag) {
    if (blockIdx.x == 0 && threadIdx.x == 0) {
        int ok = 1;
        for (int k = 0; k < 64; ++k)
            if (ei32[2 * k + 1] != 0) { ok = 0; break; }
        *flag = ok;   // 1 => int64, 0 => int32
    }
}

__device__ inline long long load_idx(const void* p, long long i, int is64) {
    if (is64) return ((const long long*)p)[i];
    return (long long)((const int*)p)[i];
}

// ne[i][j] = b_conv[j];  deg[i] = 1.0 (self-loop pre-counted)
__global__ __launch_bounds__(256) void init_kernel(float* __restrict__ ne,
                                                   float* __restrict__ deg,
                                                   const float* __restrict__ b_conv) {
    int idx = blockIdx.x * 256 + threadIdx.x;
    if (idx < NN * FH) ne[idx] = b_conv[idx & (FH - 1)];
    if (idx < NN) deg[idx] = 1.0f;
}

// h = x @ W_conv   (NN x FIN) @ (FIN x FH), fp32 vector ALU
// block: 256 threads. thread t: col = t&63, kseg = t>>6 (4 k-segments of 64)
// W[kseg*64+kk][col] held in 64 VGPRs per thread. 4 rows per iteration.
__global__ __launch_bounds__(256) void gemm_kernel(const float* __restrict__ x,
                                                   const float* __restrict__ W,
                                                   float* __restrict__ h) {
    __shared__ float xs[4 * FIN];          // 4 rows of x (4 KB)
    __shared__ float part[4][4][FH];       // [row][kseg][col] (4 KB)

    const int col = threadIdx.x & 63;
    const int kseg = threadIdx.x >> 6;

    float wreg[64];
#pragma unroll
    for (int kk = 0; kk < 64; ++kk)
        wreg[kk] = W[(kseg * 64 + kk) * FH + col];

    for (int row0 = blockIdx.x * 4; row0 < NN; row0 += gridDim.x * 4) {
        // cooperative load of 4 x-rows (1024 floats) via float4
        const float4* xv = (const float4*)(x + (long long)row0 * FIN);
        ((float4*)xs)[threadIdx.x] = xv[threadIdx.x];
        __syncthreads();

        float acc[4] = {0.f, 0.f, 0.f, 0.f};
#pragma unroll
        for (int kk = 0; kk < 64; ++kk) {
            const float w = wreg[kk];
            const int k = kseg * 64 + kk;
#pragma unroll
            for (int r = 0; r < 4; ++r)
                acc[r] += xs[r * FIN + k] * w;   // xs read is wave-uniform broadcast
        }
#pragma unroll
        for (int r = 0; r < 4; ++r) part[r][kseg][col] = acc[r];
        __syncthreads();

        // thread t -> (row = t>>6, col = t&63): sum the 4 k-segment partials
        const int row = threadIdx.x >> 6;
        float s = part[row][0][col] + part[row][1][col] + part[row][2][col] + part[row][3][col];
        h[(long long)(row0 + row) * FH + col] = s;
        __syncthreads();
    }
}

// deg[dst] += 1 over the E real edges
__global__ __launch_bounds__(256) void deg_kernel(const void* __restrict__ ei,
                                                  float* __restrict__ deg,
                                                  int E, const int* __restrict__ flag) {
    int e = blockIdx.x * 256 + threadIdx.x;
    if (e >= E) return;
    long long d = load_idx(ei, (long long)E + e, *flag);
    atomicAdd(&deg[d], 1.0f);
}

// deg -> rsqrt(deg) in place (deg >= 1 always, self-loops)
__global__ __launch_bounds__(256) void rsqrt_kernel(float* __restrict__ deg) {
    int i = blockIdx.x * 256 + threadIdx.x;
    if (i < NN) deg[i] = rsqrtf(deg[i]);
}

// self-loop contribution: ne[i][:] += h[i][:] * dinv[i]^2   (no atomics needed)
__global__ __launch_bounds__(256) void selfloop_kernel(const float* __restrict__ h,
                                                       const float* __restrict__ dinv,
                                                       float* __restrict__ ne) {
    int idx = blockIdx.x * 256 + threadIdx.x;
    if (idx >= NN * FH) return;
    int i = idx >> 6;
    float di = dinv[i];
    ne[idx] += h[idx] * di * di;
}

// edge aggregation: ne[dst][:] += h[src][:] * dinv[src]*dinv[dst]
// 16 lanes per edge, float4 gather, 4 scalar atomics per lane
__global__ __launch_bounds__(256) void edge_agg_kernel(const void* __restrict__ ei,
                                                       const float* __restrict__ dinv,
                                                       const float* __restrict__ h,
                                                       float* __restrict__ ne,
                                                       int E, const int* __restrict__ flag) {
    long long t = (long long)blockIdx.x * 256 + threadIdx.x;
    long long e = t >> 4;
    int sub = (int)(t & 15);
    if (e >= E) return;
    int is64 = *flag;
    long long s = load_idx(ei, e, is64);
    long long d = load_idx(ei, (long long)E + e, is64);
    float nrm = dinv[s] * dinv[d];
    float4 hv = *(const float4*)(h + s * FH + sub * 4);
    float* np_ = ne + d * FH + sub * 4;
    atomicAdd(np_ + 0, hv.x * nrm);
    atomicAdd(np_ + 1, hv.y * nrm);
    atomicAdd(np_ + 2, hv.z * nrm);
    atomicAdd(np_ + 3, hv.w * nrm);
}

// MLP head: gather pair, leaky, (128x16) + leaky, (16x1) + sigmoid.
// One wave per pair; lane j holds concat[j] and concat[64+j].
__global__ __launch_bounds__(256) void mlp_kernel(const float* __restrict__ ne,
                                                  const void* __restrict__ idx,
                                                  const float* __restrict__ W1,
                                                  const float* __restrict__ b1,
                                                  const float* __restrict__ W2,
                                                  const float* __restrict__ b2,
                                                  float* __restrict__ out,
                                                  int B, const int* __restrict__ flag) {
    const int lane = threadIdx.x & 63;
    const int wid = threadIdx.x >> 6;

    float w1a[16], w1b[16], b1r[16], w2r[16];
#pragma unroll
    for (int o = 0; o < 16; ++o) {
        w1a[o] = W1[lane * 16 + o];
        w1b[o] = W1[(64 + lane) * 16 + o];
        b1r[o] = b1[o];
        w2r[o] = W2[o];
    }
    const float b2v = b2[0];
    const int is64 = *flag;

    for (int pair = blockIdx.x * 4 + wid; pair < B; pair += gridDim.x * 4) {
        long long i0 = load_idx(idx, 2LL * pair, is64);
        long long i1 = load_idx(idx, 2LL * pair + 1, is64);
        float a = ne[i0 * FH + lane];
        a = a >= 0.f ? a : NEG * a;
        float b = ne[i1 * FH + lane];
        b = b >= 0.f ? b : NEG * b;

        float acc[16];
#pragma unroll
        for (int o = 0; o < 16; ++o) acc[o] = a * w1a[o] + b * w1b[o];
#pragma unroll
        for (int m = 1; m < 64; m <<= 1) {
#pragma unroll
            for (int o = 0; o < 16; ++o) acc[o] += __shfl_xor(acc[o], m, 64);
        }
        if (lane == 0) {
            float s = b2v;
#pragma unroll
            for (int o = 0; o < 16; ++o) {
                float z = acc[o] + b1r[o];
                z = z >= 0.f ? z : NEG * z;
                s += z * w2r[o];
            }
            out[pair] = 1.f / (1.f + expf(-s));
        }
    }
}

extern "C" void kernel_launch(void* const* d_in, const int* in_sizes, int n_in,
                              void* d_out, int out_size, void* d_ws, size_t ws_size,
                              hipStream_t stream) {
    const float* x      = (const float*)d_in[0];
    const void*  ei     = d_in[1];
    const void*  index  = d_in[2];
    const float* W_conv = (const float*)d_in[3];
    const float* b_conv = (const float*)d_in[4];
    const float* W1     = (const float*)d_in[5];
    const float* b1     = (const float*)d_in[6];
    const float* W2     = (const float*)d_in[7];
    const float* b2     = (const float*)d_in[8];
    float* out = (float*)d_out;

    const int E = in_sizes[1] / 2;   // 1.6M
    const int B = in_sizes[2] / 2;   // 16384

    float* h   = (float*)d_ws;
    float* ne  = h + (long long)NN * FH;
    float* deg = ne + (long long)NN * FH;
    int* flag  = (int*)(deg + NN);

    detect_kernel<<<1, 64, 0, stream>>>((const int*)ei, flag);
    init_kernel<<<(NN * FH + 255) / 256, 256, 0, stream>>>(ne, deg, b_conv);
    gemm_kernel<<<2048, 256, 0, stream>>>(x, W_conv, h);
    deg_kernel<<<(E + 255) / 256, 256, 0, stream>>>(ei, deg, E, flag);
    rsqrt_kernel<<<(NN + 255) / 256, 256, 0, stream>>>(deg);
    selfloop_kernel<<<(NN * FH + 255) / 256, 256, 0, stream>>>(h, deg, ne);
    edge_agg_kernel<<<(int)(((long long)E * 16 + 255) / 256), 256, 0, stream>>>(ei, deg, h, ne, E, flag);
    mlp_kernel<<<512, 256, 0, stream>>>(ne, index, W1, b1, W2, b2, out, B, flag);
}

// Round 2
// 510.913 us; speedup vs baseline: 3.0621x; 3.0621x over previous
//
#include <hip/hip_runtime.h>
#include <hip/hip_bf16.h>

#define NN 100000      // nodes
#define FIN 256        // input features
#define FH 64          // hidden features
#define NEG 0.01f

// ---------------------------------------------------------------------------
// ws layout (new path), floats/ints:
//   h[NN*FH] | ne[NN*FH] | dinv[NN] | cursor[NN] | bucket[E] | flag(int)
// Fallback path (ws too small): h | ne | deg | flag  (round-1 atomic scatter)
// ---------------------------------------------------------------------------

// Detect whether index buffers are int64 (hi words zero) or int32.
__global__ void detect_kernel(const int* __restrict__ ei32, int* __restrict__ flag) {
    if (blockIdx.x == 0 && threadIdx.x == 0) {
        int ok = 1;
        for (int k = 0; k < 64; ++k)
            if (ei32[2 * k + 1] != 0) { ok = 0; break; }
        *flag = ok;   // 1 => int64, 0 => int32
    }
}

__device__ inline long long load_idx(const void* p, long long i, int is64) {
    if (is64) return ((const long long*)p)[i];
    return (long long)((const int*)p)[i];
}

// h = x @ W_conv   (NN x FIN) @ (FIN x FH), fp32 vector ALU
__global__ __launch_bounds__(256) void gemm_kernel(const float* __restrict__ x,
                                                   const float* __restrict__ W,
                                                   float* __restrict__ h) {
    __shared__ float xs[4 * FIN];
    __shared__ float part[4][4][FH];

    const int col = threadIdx.x & 63;
    const int kseg = threadIdx.x >> 6;

    float wreg[64];
#pragma unroll
    for (int kk = 0; kk < 64; ++kk)
        wreg[kk] = W[(kseg * 64 + kk) * FH + col];

    for (int row0 = blockIdx.x * 4; row0 < NN; row0 += gridDim.x * 4) {
        const float4* xv = (const float4*)(x + (long long)row0 * FIN);
        ((float4*)xs)[threadIdx.x] = xv[threadIdx.x];
        __syncthreads();

        float acc[4] = {0.f, 0.f, 0.f, 0.f};
#pragma unroll
        for (int kk = 0; kk < 64; ++kk) {
            const float w = wreg[kk];
            const int k = kseg * 64 + kk;
#pragma unroll
            for (int r = 0; r < 4; ++r)
                acc[r] += xs[r * FIN + k] * w;
        }
#pragma unroll
        for (int r = 0; r < 4; ++r) part[r][kseg][col] = acc[r];
        __syncthreads();

        const int row = threadIdx.x >> 6;
        float s = part[row][0][col] + part[row][1][col] + part[row][2][col] + part[row][3][col];
        h[(long long)(row0 + row) * FH + col] = s;
        __syncthreads();
    }
}

// ------------------------- CSR pull path -----------------------------------

__global__ __launch_bounds__(256) void zero_kernel(int* __restrict__ cursor) {
    int i = blockIdx.x * 256 + threadIdx.x;
    if (i < NN) cursor[i] = 0;
}

// cursor[dst] += 1 over the E real edges (int atomics)
__global__ __launch_bounds__(256) void count_kernel(const void* __restrict__ ei,
                                                    int* __restrict__ cursor,
                                                    int E, const int* __restrict__ flag) {
    int e = blockIdx.x * 256 + threadIdx.x;
    if (e >= E) return;
    long long d = load_idx(ei, (long long)E + e, *flag);
    atomicAdd(&cursor[d], 1);
}

// dinv[i] = rsqrt(1 + indeg) ; (self-loop included)
__global__ __launch_bounds__(256) void dinv_kernel(const int* __restrict__ cursor,
                                                   float* __restrict__ dinv) {
    int i = blockIdx.x * 256 + threadIdx.x;
    if (i < NN) dinv[i] = rsqrtf(1.0f + (float)cursor[i]);
}

// exclusive prefix sum of cursor[NN], single block of 256 threads
__global__ __launch_bounds__(256) void scan_kernel(int* __restrict__ cursor) {
    __shared__ int part[256];
    const int CH = (NN + 255) / 256;   // 391
    const int t = threadIdx.x;
    const int lo = t * CH;
    const int hi = lo + CH < NN ? lo + CH : NN;
    int s = 0;
    for (int i = lo; i < hi; ++i) s += cursor[i];
    part[t] = s;
    __syncthreads();
    if (t == 0) {
        int acc = 0;
        for (int i = 0; i < 256; ++i) { int v = part[i]; part[i] = acc; acc += v; }
    }
    __syncthreads();
    int acc = part[t];
    for (int i = lo; i < hi; ++i) { int v = cursor[i]; cursor[i] = acc; acc += v; }
}

// bucket[pos] = src, pos = cursor[dst]++.  After this, cursor[i] = row end.
__global__ __launch_bounds__(256) void fill_kernel(const void* __restrict__ ei,
                                                   int* __restrict__ cursor,
                                                   int* __restrict__ bucket,
                                                   int E, const int* __restrict__ flag) {
    int e = blockIdx.x * 256 + threadIdx.x;
    if (e >= E) return;
    int is64 = *flag;
    long long s = load_idx(ei, e, is64);
    long long d = load_idx(ei, (long long)E + e, is64);
    int pos = atomicAdd(&cursor[d], 1);
    bucket[pos] = (int)s;
}

// one wave per node: pull-sum incoming messages, add self-loop + bias, leaky.
// lane: sub = lane&15 (float4 chunk of the 64-wide row), eg = lane>>4 (edge group)
__global__ __launch_bounds__(256) void gather_kernel(const float* __restrict__ h,
                                                     const float* __restrict__ dinv,
                                                     const int* __restrict__ cursor,
                                                     const int* __restrict__ bucket,
                                                     const float* __restrict__ b_conv,
                                                     float* __restrict__ ne) {
    const int node = blockIdx.x * 4 + (threadIdx.x >> 6);
    if (node >= NN) return;
    const int lane = threadIdx.x & 63;
    const int sub = lane & 15;
    const int eg = lane >> 4;

    const int end = cursor[node];
    const int base = node ? cursor[node - 1] : 0;
    const float dd = dinv[node];

    float4 acc = make_float4(0.f, 0.f, 0.f, 0.f);
    for (int k = base + eg; k < end; k += 4) {
        int s = bucket[k];
        float nrm = dinv[s] * dd;
        float4 hv = *(const float4*)(h + (long long)s * FH + sub * 4);
        acc.x += hv.x * nrm; acc.y += hv.y * nrm;
        acc.z += hv.z * nrm; acc.w += hv.w * nrm;
    }
#pragma unroll
    for (int m = 16; m < 64; m <<= 1) {
        acc.x += __shfl_xor(acc.x, m);
        acc.y += __shfl_xor(acc.y, m);
        acc.z += __shfl_xor(acc.z, m);
        acc.w += __shfl_xor(acc.w, m);
    }
    if (eg == 0) {
        float4 hv = *(const float4*)(h + (long long)node * FH + sub * 4);
        float4 bc = *(const float4*)(b_conv + sub * 4);
        float4 r;
        r.x = acc.x + hv.x * dd * dd + bc.x;
        r.y = acc.y + hv.y * dd * dd + bc.y;
        r.z = acc.z + hv.z * dd * dd + bc.z;
        r.w = acc.w + hv.w * dd * dd + bc.w;
        r.x = r.x >= 0.f ? r.x : NEG * r.x;
        r.y = r.y >= 0.f ? r.y : NEG * r.y;
        r.z = r.z >= 0.f ? r.z : NEG * r.z;
        r.w = r.w >= 0.f ? r.w : NEG * r.w;
        *(float4*)(ne + (long long)node * FH + sub * 4) = r;
    }
}

// ------------------------- fallback (round-1) path --------------------------

__global__ __launch_bounds__(256) void init_kernel(float* __restrict__ ne,
                                                   float* __restrict__ deg,
                                                   const float* __restrict__ b_conv) {
    int idx = blockIdx.x * 256 + threadIdx.x;
    if (idx < NN * FH) ne[idx] = b_conv[idx & (FH - 1)];
    if (idx < NN) deg[idx] = 1.0f;
}

__global__ __launch_bounds__(256) void deg_kernel(const void* __restrict__ ei,
                                                  float* __restrict__ deg,
                                                  int E, const int* __restrict__ flag) {
    int e = blockIdx.x * 256 + threadIdx.x;
    if (e >= E) return;
    long long d = load_idx(ei, (long long)E + e, *flag);
    atomicAdd(&deg[d], 1.0f);
}

__global__ __launch_bounds__(256) void rsqrt_kernel(float* __restrict__ deg) {
    int i = blockIdx.x * 256 + threadIdx.x;
    if (i < NN) deg[i] = rsqrtf(deg[i]);
}

__global__ __launch_bounds__(256) void selfloop_kernel(const float* __restrict__ h,
                                                       const float* __restrict__ dinv,
                                                       float* __restrict__ ne) {
    int idx = blockIdx.x * 256 + threadIdx.x;
    if (idx >= NN * FH) return;
    int i = idx >> 6;
    float di = dinv[i];
    ne[idx] += h[idx] * di * di;
}

__global__ __launch_bounds__(256) void edge_agg_kernel(const void* __restrict__ ei,
                                                       const float* __restrict__ dinv,
                                                       const float* __restrict__ h,
                                                       float* __restrict__ ne,
                                                       int E, const int* __restrict__ flag) {
    long long t = (long long)blockIdx.x * 256 + threadIdx.x;
    long long e = t >> 4;
    int sub = (int)(t & 15);
    if (e >= E) return;
    int is64 = *flag;
    long long s = load_idx(ei, e, is64);
    long long d = load_idx(ei, (long long)E + e, is64);
    float nrm = dinv[s] * dinv[d];
    float4 hv = *(const float4*)(h + s * FH + sub * 4);
    float* np_ = ne + d * FH + sub * 4;
    atomicAdd(np_ + 0, hv.x * nrm);
    atomicAdd(np_ + 1, hv.y * nrm);
    atomicAdd(np_ + 2, hv.z * nrm);
    atomicAdd(np_ + 3, hv.w * nrm);
}

// ------------------------- MLP head -----------------------------------------
// pre_act=1: apply leaky to gathered ne rows (fallback); 0: ne already activated
__global__ __launch_bounds__(256) void mlp_kernel(const float* __restrict__ ne,
                                                  const void* __restrict__ idx,
                                                  const float* __restrict__ W1,
                                                  const float* __restrict__ b1,
                                                  const float* __restrict__ W2,
                                                  const float* __restrict__ b2,
                                                  float* __restrict__ out,
                                                  int B, const int* __restrict__ flag,
                                                  int pre_act) {
    const int lane = threadIdx.x & 63;
    const int wid = threadIdx.x >> 6;

    float w1a[16], w1b[16], b1r[16], w2r[16];
#pragma unroll
    for (int o = 0; o < 16; ++o) {
        w1a[o] = W1[lane * 16 + o];
        w1b[o] = W1[(64 + lane) * 16 + o];
        b1r[o] = b1[o];
        w2r[o] = W2[o];
    }
    const float b2v = b2[0];
    const int is64 = *flag;

    for (int pair = blockIdx.x * 4 + wid; pair < B; pair += gridDim.x * 4) {
        long long i0 = load_idx(idx, 2LL * pair, is64);
        long long i1 = load_idx(idx, 2LL * pair + 1, is64);
        float a = ne[i0 * FH + lane];
        float b = ne[i1 * FH + lane];
        if (pre_act) {
            a = a >= 0.f ? a : NEG * a;
            b = b >= 0.f ? b : NEG * b;
        }

        float acc[16];
#pragma unroll
        for (int o = 0; o < 16; ++o) acc[o] = a * w1a[o] + b * w1b[o];
#pragma unroll
        for (int m = 1; m < 64; m <<= 1) {
#pragma unroll
            for (int o = 0; o < 16; ++o) acc[o] += __shfl_xor(acc[o], m, 64);
        }
        if (lane == 0) {
            float s = b2v;
#pragma unroll
            for (int o = 0; o < 16; ++o) {
                float z = acc[o] + b1r[o];
                z = z >= 0.f ? z : NEG * z;
                s += z * w2r[o];
            }
            out[pair] = 1.f / (1.f + expf(-s));
        }
    }
}

extern "C" void kernel_launch(void* const* d_in, const int* in_sizes, int n_in,
                              void* d_out, int out_size, void* d_ws, size_t ws_size,
                              hipStream_t stream) {
    const float* x      = (const float*)d_in[0];
    const void*  ei     = d_in[1];
    const void*  index  = d_in[2];
    const float* W_conv = (const float*)d_in[3];
    const float* b_conv = (const float*)d_in[4];
    const float* W1     = (const float*)d_in[5];
    const float* b1     = (const float*)d_in[6];
    const float* W2     = (const float*)d_in[7];
    const float* b2     = (const float*)d_in[8];
    float* out = (float*)d_out;

    const int E = in_sizes[1] / 2;   // 1.6M
    const int B = in_sizes[2] / 2;   // 16384

    float* h  = (float*)d_ws;
    float* ne = h + (long long)NN * FH;

    const size_t need_new = ((size_t)2 * NN * FH + 2 * NN + (size_t)E + 4) * 4;

    if (ws_size >= need_new) {
        // CSR pull path
        float* dinv   = ne + (long long)NN * FH;
        int*   cursor = (int*)(dinv + NN);
        int*   bucket = cursor + NN;
        int*   flag   = bucket + E;

        detect_kernel<<<1, 64, 0, stream>>>((const int*)ei, flag);
        zero_kernel<<<(NN + 255) / 256, 256, 0, stream>>>(cursor);
        gemm_kernel<<<2048, 256, 0, stream>>>(x, W_conv, h);
        count_kernel<<<(E + 255) / 256, 256, 0, stream>>>(ei, cursor, E, flag);
        dinv_kernel<<<(NN + 255) / 256, 256, 0, stream>>>(cursor, dinv);
        scan_kernel<<<1, 256, 0, stream>>>(cursor);
        fill_kernel<<<(E + 255) / 256, 256, 0, stream>>>(ei, cursor, bucket, E, flag);
        gather_kernel<<<(NN + 3) / 4, 256, 0, stream>>>(h, dinv, cursor, bucket, b_conv, ne);
        mlp_kernel<<<512, 256, 0, stream>>>(ne, index, W1, b1, W2, b2, out, B, flag, 0);
    } else {
        // fallback: round-1 atomic scatter
        float* deg = ne + (long long)NN * FH;
        int* flag  = (int*)(deg + NN);

        detect_kernel<<<1, 64, 0, stream>>>((const int*)ei, flag);
        init_kernel<<<(NN * FH + 255) / 256, 256, 0, stream>>>(ne, deg, b_conv);
        gemm_kernel<<<2048, 256, 0, stream>>>(x, W_conv, h);
        deg_kernel<<<(E + 255) / 256, 256, 0, stream>>>(ei, deg, E, flag);
        rsqrt_kernel<<<(NN + 255) / 256, 256, 0, stream>>>(deg);
        selfloop_kernel<<<(NN * FH + 255) / 256, 256, 0, stream>>>(h, deg, ne);
        edge_agg_kernel<<<(int)(((long long)E * 16 + 255) / 256), 256, 0, stream>>>(ei, deg, h, ne, E, flag);
        mlp_kernel<<<512, 256, 0, stream>>>(ne, index, W1, b1, W2, b2, out, B, flag, 1);
    }
}

// Round 3
// 353.448 us; speedup vs baseline: 4.4263x; 1.4455x over previous
//
#include <hip/hip_runtime.h>
#include <hip/hip_bf16.h>

#define NN 100000      // nodes
#define FIN 256        // input features
#define FH 64          // hidden features
#define NEG 0.01f
#define SCAN_CH 2048
#define NBLK_SCAN ((NN + SCAN_CH - 1) / SCAN_CH)   // 49

// ---------------------------------------------------------------------------
// ws layout (new path), floats/ints:
//   h[NN*FH] | ne[NN*FH] | dinv[NN] | cursor[NN] | bucket[E] | flag(int) | partials[NBLK_SCAN]
// Fallback path (ws too small): h | ne | deg | flag  (round-1 atomic scatter)
// ---------------------------------------------------------------------------

// Detect whether index buffers are int64 (hi words zero) or int32.
__global__ void detect_kernel(const int* __restrict__ ei32, int* __restrict__ flag) {
    if (blockIdx.x == 0 && threadIdx.x == 0) {
        int ok = 1;
        for (int k = 0; k < 64; ++k)
            if (ei32[2 * k + 1] != 0) { ok = 0; break; }
        *flag = ok;   // 1 => int64, 0 => int32
    }
}

__device__ inline long long load_idx(const void* p, long long i, int is64) {
    if (is64) return ((const long long*)p)[i];
    return (long long)((const int*)p)[i];
}

// h = x @ W_conv   (NN x FIN) @ (FIN x FH), fp32 vector ALU
__global__ __launch_bounds__(256) void gemm_kernel(const float* __restrict__ x,
                                                   const float* __restrict__ W,
                                                   float* __restrict__ h) {
    __shared__ float xs[4 * FIN];
    __shared__ float part[4][4][FH];

    const int col = threadIdx.x & 63;
    const int kseg = threadIdx.x >> 6;

    float wreg[64];
#pragma unroll
    for (int kk = 0; kk < 64; ++kk)
        wreg[kk] = W[(kseg * 64 + kk) * FH + col];

    for (int row0 = blockIdx.x * 4; row0 < NN; row0 += gridDim.x * 4) {
        const float4* xv = (const float4*)(x + (long long)row0 * FIN);
        ((float4*)xs)[threadIdx.x] = xv[threadIdx.x];
        __syncthreads();

        float acc[4] = {0.f, 0.f, 0.f, 0.f};
#pragma unroll
        for (int kk = 0; kk < 64; ++kk) {
            const float w = wreg[kk];
            const int k = kseg * 64 + kk;
#pragma unroll
            for (int r = 0; r < 4; ++r)
                acc[r] += xs[r * FIN + k] * w;
        }
#pragma unroll
        for (int r = 0; r < 4; ++r) part[r][kseg][col] = acc[r];
        __syncthreads();

        const int row = threadIdx.x >> 6;
        float s = part[row][0][col] + part[row][1][col] + part[row][2][col] + part[row][3][col];
        h[(long long)(row0 + row) * FH + col] = s;
        __syncthreads();
    }
}

// ------------------------- CSR pull path -----------------------------------

__global__ __launch_bounds__(256) void zero_kernel(int* __restrict__ cursor) {
    int i = blockIdx.x * 256 + threadIdx.x;
    if (i < NN) cursor[i] = 0;
}

// cursor[dst] += 1 over the E real edges (int atomics)
__global__ __launch_bounds__(256) void count_kernel(const void* __restrict__ ei,
                                                    int* __restrict__ cursor,
                                                    int E, const int* __restrict__ flag) {
    int e = blockIdx.x * 256 + threadIdx.x;
    if (e >= E) return;
    long long d = load_idx(ei, (long long)E + e, *flag);
    atomicAdd(&cursor[d], 1);
}

// dinv[i] = rsqrt(1 + indeg) ; (self-loop included)
__global__ __launch_bounds__(256) void dinv_kernel(const int* __restrict__ cursor,
                                                   float* __restrict__ dinv) {
    int i = blockIdx.x * 256 + threadIdx.x;
    if (i < NN) dinv[i] = rsqrtf(1.0f + (float)cursor[i]);
}

// ---- 3-phase exclusive scan of cursor[NN] ----
// A: per-block (2048 elems) sum -> partials[b]
__global__ __launch_bounds__(256) void scanA_kernel(const int* __restrict__ cursor,
                                                    int* __restrict__ partials) {
    const int t = threadIdx.x;
    const int base = blockIdx.x * SCAN_CH + t * 8;
    int s = 0;
#pragma unroll
    for (int i = 0; i < 8; ++i) {
        int idx = base + i;
        if (idx < NN) s += cursor[idx];
    }
#pragma unroll
    for (int m = 1; m < 64; m <<= 1) s += __shfl_xor(s, m, 64);
    __shared__ int ws[4];
    if ((t & 63) == 0) ws[t >> 6] = s;
    __syncthreads();
    if (t == 0) partials[blockIdx.x] = ws[0] + ws[1] + ws[2] + ws[3];
}

// B: one wave exclusive-scans partials[NBLK_SCAN]  (NBLK_SCAN <= 64)
__global__ __launch_bounds__(64) void scanB_kernel(int* __restrict__ partials) {
    const int t = threadIdx.x;
    int v = (t < NBLK_SCAN) ? partials[t] : 0;
#pragma unroll
    for (int m = 1; m < 64; m <<= 1) {
        int u = __shfl_up(v, m, 64);
        if (t >= m) v += u;
    }
    int ex = __shfl_up(v, 1, 64);
    if (t == 0) ex = 0;
    if (t < NBLK_SCAN) partials[t] = ex;
}

// C: per-chunk exclusive scan + chunk offset
__global__ __launch_bounds__(256) void scanC_kernel(int* __restrict__ cursor,
                                                    const int* __restrict__ partials) {
    const int t = threadIdx.x;
    const int lane = t & 63, w = t >> 6;
    const int base = blockIdx.x * SCAN_CH + t * 8;
    int vals[8];
    int s = 0;
#pragma unroll
    for (int i = 0; i < 8; ++i) {
        int idx = base + i;
        vals[i] = (idx < NN) ? cursor[idx] : 0;
        s += vals[i];
    }
    int incl = s;
#pragma unroll
    for (int m = 1; m < 64; m <<= 1) {
        int u = __shfl_up(incl, m, 64);
        if (lane >= m) incl += u;
    }
    __shared__ int wsum[4];
    if (lane == 63) wsum[w] = incl;
    __syncthreads();
    int woff = partials[blockIdx.x];
    for (int i = 0; i < w; ++i) woff += wsum[i];
    int ex = incl - s + woff;
#pragma unroll
    for (int i = 0; i < 8; ++i) {
        int idx = base + i;
        if (idx < NN) cursor[idx] = ex;
        ex += vals[i];
    }
}

// bucket[pos] = src, pos = cursor[dst]++.  After this, cursor[i] = row end.
__global__ __launch_bounds__(256) void fill_kernel(const void* __restrict__ ei,
                                                   int* __restrict__ cursor,
                                                   int* __restrict__ bucket,
                                                   int E, const int* __restrict__ flag) {
    int e = blockIdx.x * 256 + threadIdx.x;
    if (e >= E) return;
    int is64 = *flag;
    long long s = load_idx(ei, e, is64);
    long long d = load_idx(ei, (long long)E + e, is64);
    int pos = atomicAdd(&cursor[d], 1);
    bucket[pos] = (int)s;
}

// one wave per node: pull-sum incoming messages, add self-loop + bias, leaky.
__global__ __launch_bounds__(256) void gather_kernel(const float* __restrict__ h,
                                                     const float* __restrict__ dinv,
                                                     const int* __restrict__ cursor,
                                                     const int* __restrict__ bucket,
                                                     const float* __restrict__ b_conv,
                                                     float* __restrict__ ne) {
    const int node = blockIdx.x * 4 + (threadIdx.x >> 6);
    if (node >= NN) return;
    const int lane = threadIdx.x & 63;
    const int sub = lane & 15;
    const int eg = lane >> 4;

    const int end = cursor[node];
    const int base = node ? cursor[node - 1] : 0;
    const float dd = dinv[node];

    float4 acc = make_float4(0.f, 0.f, 0.f, 0.f);
    for (int k = base + eg; k < end; k += 4) {
        int s = bucket[k];
        float nrm = dinv[s] * dd;
        float4 hv = *(const float4*)(h + (long long)s * FH + sub * 4);
        acc.x += hv.x * nrm; acc.y += hv.y * nrm;
        acc.z += hv.z * nrm; acc.w += hv.w * nrm;
    }
#pragma unroll
    for (int m = 16; m < 64; m <<= 1) {
        acc.x += __shfl_xor(acc.x, m);
        acc.y += __shfl_xor(acc.y, m);
        acc.z += __shfl_xor(acc.z, m);
        acc.w += __shfl_xor(acc.w, m);
    }
    if (eg == 0) {
        float4 hv = *(const float4*)(h + (long long)node * FH + sub * 4);
        float4 bc = *(const float4*)(b_conv + sub * 4);
        float4 r;
        r.x = acc.x + hv.x * dd * dd + bc.x;
        r.y = acc.y + hv.y * dd * dd + bc.y;
        r.z = acc.z + hv.z * dd * dd + bc.z;
        r.w = acc.w + hv.w * dd * dd + bc.w;
        r.x = r.x >= 0.f ? r.x : NEG * r.x;
        r.y = r.y >= 0.f ? r.y : NEG * r.y;
        r.z = r.z >= 0.f ? r.z : NEG * r.z;
        r.w = r.w >= 0.f ? r.w : NEG * r.w;
        *(float4*)(ne + (long long)node * FH + sub * 4) = r;
    }
}

// ------------------------- fallback (round-1) path --------------------------

__global__ __launch_bounds__(256) void init_kernel(float* __restrict__ ne,
                                                   float* __restrict__ deg,
                                                   const float* __restrict__ b_conv) {
    int idx = blockIdx.x * 256 + threadIdx.x;
    if (idx < NN * FH) ne[idx] = b_conv[idx & (FH - 1)];
    if (idx < NN) deg[idx] = 1.0f;
}

__global__ __launch_bounds__(256) void deg_kernel(const void* __restrict__ ei,
                                                  float* __restrict__ deg,
                                                  int E, const int* __restrict__ flag) {
    int e = blockIdx.x * 256 + threadIdx.x;
    if (e >= E) return;
    long long d = load_idx(ei, (long long)E + e, *flag);
    atomicAdd(&deg[d], 1.0f);
}

__global__ __launch_bounds__(256) void rsqrt_kernel(float* __restrict__ deg) {
    int i = blockIdx.x * 256 + threadIdx.x;
    if (i < NN) deg[i] = rsqrtf(deg[i]);
}

__global__ __launch_bounds__(256) void selfloop_kernel(const float* __restrict__ h,
                                                       const float* __restrict__ dinv,
                                                       float* __restrict__ ne) {
    int idx = blockIdx.x * 256 + threadIdx.x;
    if (idx >= NN * FH) return;
    int i = idx >> 6;
    float di = dinv[i];
    ne[idx] += h[idx] * di * di;
}

__global__ __launch_bounds__(256) void edge_agg_kernel(const void* __restrict__ ei,
                                                       const float* __restrict__ dinv,
                                                       const float* __restrict__ h,
                                                       float* __restrict__ ne,
                                                       int E, const int* __restrict__ flag) {
    long long t = (long long)blockIdx.x * 256 + threadIdx.x;
    long long e = t >> 4;
    int sub = (int)(t & 15);
    if (e >= E) return;
    int is64 = *flag;
    long long s = load_idx(ei, e, is64);
    long long d = load_idx(ei, (long long)E + e, is64);
    float nrm = dinv[s] * dinv[d];
    float4 hv = *(const float4*)(h + s * FH + sub * 4);
    float* np_ = ne + d * FH + sub * 4;
    atomicAdd(np_ + 0, hv.x * nrm);
    atomicAdd(np_ + 1, hv.y * nrm);
    atomicAdd(np_ + 2, hv.z * nrm);
    atomicAdd(np_ + 3, hv.w * nrm);
}

// ------------------------- MLP head -----------------------------------------
__global__ __launch_bounds__(256) void mlp_kernel(const float* __restrict__ ne,
                                                  const void* __restrict__ idx,
                                                  const float* __restrict__ W1,
                                                  const float* __restrict__ b1,
                                                  const float* __restrict__ W2,
                                                  const float* __restrict__ b2,
                                                  float* __restrict__ out,
                                                  int B, const int* __restrict__ flag,
                                                  int pre_act) {
    const int lane = threadIdx.x & 63;
    const int wid = threadIdx.x >> 6;

    float w1a[16], w1b[16], b1r[16], w2r[16];
#pragma unroll
    for (int o = 0; o < 16; ++o) {
        w1a[o] = W1[lane * 16 + o];
        w1b[o] = W1[(64 + lane) * 16 + o];
        b1r[o] = b1[o];
        w2r[o] = W2[o];
    }
    const float b2v = b2[0];
    const int is64 = *flag;

    for (int pair = blockIdx.x * 4 + wid; pair < B; pair += gridDim.x * 4) {
        long long i0 = load_idx(idx, 2LL * pair, is64);
        long long i1 = load_idx(idx, 2LL * pair + 1, is64);
        float a = ne[i0 * FH + lane];
        float b = ne[i1 * FH + lane];
        if (pre_act) {
            a = a >= 0.f ? a : NEG * a;
            b = b >= 0.f ? b : NEG * b;
        }

        float acc[16];
#pragma unroll
        for (int o = 0; o < 16; ++o) acc[o] = a * w1a[o] + b * w1b[o];
#pragma unroll
        for (int m = 1; m < 64; m <<= 1) {
#pragma unroll
            for (int o = 0; o < 16; ++o) acc[o] += __shfl_xor(acc[o], m, 64);
        }
        if (lane == 0) {
            float s = b2v;
#pragma unroll
            for (int o = 0; o < 16; ++o) {
                float z = acc[o] + b1r[o];
                z = z >= 0.f ? z : NEG * z;
                s += z * w2r[o];
            }
            out[pair] = 1.f / (1.f + expf(-s));
        }
    }
}

extern "C" void kernel_launch(void* const* d_in, const int* in_sizes, int n_in,
                              void* d_out, int out_size, void* d_ws, size_t ws_size,
                              hipStream_t stream) {
    const float* x      = (const float*)d_in[0];
    const void*  ei     = d_in[1];
    const void*  index  = d_in[2];
    const float* W_conv = (const float*)d_in[3];
    const float* b_conv = (const float*)d_in[4];
    const float* W1     = (const float*)d_in[5];
    const float* b1     = (const float*)d_in[6];
    const float* W2     = (const float*)d_in[7];
    const float* b2     = (const float*)d_in[8];
    float* out = (float*)d_out;

    const int E = in_sizes[1] / 2;   // 1.6M
    const int B = in_sizes[2] / 2;   // 16384

    float* h  = (float*)d_ws;
    float* ne = h + (long long)NN * FH;

    const size_t need_new = ((size_t)2 * NN * FH + 2 * NN + (size_t)E + 4 + NBLK_SCAN) * 4;

    if (ws_size >= need_new) {
        // CSR pull path
        float* dinv   = ne + (long long)NN * FH;
        int*   cursor = (int*)(dinv + NN);
        int*   bucket = cursor + NN;
        int*   flag   = bucket + E;
        int*   partials = flag + 1;

        detect_kernel<<<1, 64, 0, stream>>>((const int*)ei, flag);
        zero_kernel<<<(NN + 255) / 256, 256, 0, stream>>>(cursor);
        gemm_kernel<<<2048, 256, 0, stream>>>(x, W_conv, h);
        count_kernel<<<(E + 255) / 256, 256, 0, stream>>>(ei, cursor, E, flag);
        dinv_kernel<<<(NN + 255) / 256, 256, 0, stream>>>(cursor, dinv);
        scanA_kernel<<<NBLK_SCAN, 256, 0, stream>>>(cursor, partials);
        scanB_kernel<<<1, 64, 0, stream>>>(partials);
        scanC_kernel<<<NBLK_SCAN, 256, 0, stream>>>(cursor, partials);
        fill_kernel<<<(E + 255) / 256, 256, 0, stream>>>(ei, cursor, bucket, E, flag);
        gather_kernel<<<(NN + 3) / 4, 256, 0, stream>>>(h, dinv, cursor, bucket, b_conv, ne);
        mlp_kernel<<<512, 256, 0, stream>>>(ne, index, W1, b1, W2, b2, out, B, flag, 0);
    } else {
        // fallback: round-1 atomic scatter
        float* deg = ne + (long long)NN * FH;
        int* flag  = (int*)(deg + NN);

        detect_kernel<<<1, 64, 0, stream>>>((const int*)ei, flag);
        init_kernel<<<(NN * FH + 255) / 256, 256, 0, stream>>>(ne, deg, b_conv);
        gemm_kernel<<<2048, 256, 0, stream>>>(x, W_conv, h);
        deg_kernel<<<(E + 255) / 256, 256, 0, stream>>>(ei, deg, E, flag);
        rsqrt_kernel<<<(NN + 255) / 256, 256, 0, stream>>>(deg);
        selfloop_kernel<<<(NN * FH + 255) / 256, 256, 0, stream>>>(h, deg, ne);
        edge_agg_kernel<<<(int)(((long long)E * 16 + 255) / 256), 256, 0, stream>>>(ei, deg, h, ne, E, flag);
        mlp_kernel<<<512, 256, 0, stream>>>(ne, index, W1, b1, W2, b2, out, B, flag, 1);
    }
}

// Round 4
// 285.283 us; speedup vs baseline: 5.4839x; 1.2389x over previous
//
#include <hip/hip_runtime.h>
#include <hip/hip_bf16.h>

#define NN 100000      // nodes
#define FIN 256        // input features
#define FH 64          // hidden features
#define NEG 0.01f
#define SCAN_CH 2048
#define NBLK_SCAN ((NN + SCAN_CH - 1) / SCAN_CH)   // 49
#define NBUCK 256
#define BNODES ((NN + NBUCK - 1) / NBUCK)          // 391 nodes per coarse bucket
#define P1_CH 2048

// ---------------------------------------------------------------------------
// ws layout (CSR path), 4-byte units:
//   h[NN*FH] | ne[NN*FH] (pairs int2[E] staged here pre-gather) | dinv[NN] |
//   cursor[NN+1] | bucket[E] | flag | partials[NBLK_SCAN] | coarse_cursor[NBUCK]
// Fallback (ws too small): h | ne | deg | flag  (round-1 atomic scatter)
// ---------------------------------------------------------------------------

__global__ void detect_kernel(const int* __restrict__ ei32, int* __restrict__ flag) {
    if (blockIdx.x == 0 && threadIdx.x == 0) {
        int ok = 1;
        for (int k = 0; k < 64; ++k)
            if (ei32[2 * k + 1] != 0) { ok = 0; break; }
        *flag = ok;   // 1 => int64, 0 => int32
    }
}

__device__ inline long long load_idx(const void* p, long long i, int is64) {
    if (is64) return ((const long long*)p)[i];
    return (long long)((const int*)p)[i];
}

// h = x @ W_conv   (NN x FIN) @ (FIN x FH), fp32 vector ALU
__global__ __launch_bounds__(256) void gemm_kernel(const float* __restrict__ x,
                                                   const float* __restrict__ W,
                                                   float* __restrict__ h) {
    __shared__ float xs[4 * FIN];
    __shared__ float part[4][4][FH];

    const int col = threadIdx.x & 63;
    const int kseg = threadIdx.x >> 6;

    float wreg[64];
#pragma unroll
    for (int kk = 0; kk < 64; ++kk)
        wreg[kk] = W[(kseg * 64 + kk) * FH + col];

    for (int row0 = blockIdx.x * 4; row0 < NN; row0 += gridDim.x * 4) {
        const float4* xv = (const float4*)(x + (long long)row0 * FIN);
        ((float4*)xs)[threadIdx.x] = xv[threadIdx.x];
        __syncthreads();

        float acc[4] = {0.f, 0.f, 0.f, 0.f};
#pragma unroll
        for (int kk = 0; kk < 64; ++kk) {
            const float w = wreg[kk];
            const int k = kseg * 64 + kk;
#pragma unroll
            for (int r = 0; r < 4; ++r)
                acc[r] += xs[r * FIN + k] * w;
        }
#pragma unroll
        for (int r = 0; r < 4; ++r) part[r][kseg][col] = acc[r];
        __syncthreads();

        const int row = threadIdx.x >> 6;
        float s = part[row][0][col] + part[row][1][col] + part[row][2][col] + part[row][3][col];
        h[(long long)(row0 + row) * FH + col] = s;
        __syncthreads();
    }
}

// ------------------------- CSR pull path -----------------------------------

__global__ __launch_bounds__(256) void zero_kernel(int* __restrict__ cursor) {
    int i = blockIdx.x * 256 + threadIdx.x;
    if (i < NN) cursor[i] = 0;
}

__global__ __launch_bounds__(256) void count_kernel(const void* __restrict__ ei,
                                                    int* __restrict__ cursor,
                                                    int E, const int* __restrict__ flag) {
    int e = blockIdx.x * 256 + threadIdx.x;
    if (e >= E) return;
    long long d = load_idx(ei, (long long)E + e, *flag);
    atomicAdd(&cursor[d], 1);
}

__global__ __launch_bounds__(256) void dinv_kernel(const int* __restrict__ cursor,
                                                   float* __restrict__ dinv) {
    int i = blockIdx.x * 256 + threadIdx.x;
    if (i < NN) dinv[i] = rsqrtf(1.0f + (float)cursor[i]);
}

// ---- 3-phase exclusive scan of cursor[NN]; scanC also writes cursor[NN]=E ----
__global__ __launch_bounds__(256) void scanA_kernel(const int* __restrict__ cursor,
                                                    int* __restrict__ partials) {
    const int t = threadIdx.x;
    const int base = blockIdx.x * SCAN_CH + t * 8;
    int s = 0;
#pragma unroll
    for (int i = 0; i < 8; ++i) {
        int idx = base + i;
        if (idx < NN) s += cursor[idx];
    }
#pragma unroll
    for (int m = 1; m < 64; m <<= 1) s += __shfl_xor(s, m, 64);
    __shared__ int ws[4];
    if ((t & 63) == 0) ws[t >> 6] = s;
    __syncthreads();
    if (t == 0) partials[blockIdx.x] = ws[0] + ws[1] + ws[2] + ws[3];
}

__global__ __launch_bounds__(64) void scanB_kernel(int* __restrict__ partials) {
    const int t = threadIdx.x;
    int v = (t < NBLK_SCAN) ? partials[t] : 0;
#pragma unroll
    for (int m = 1; m < 64; m <<= 1) {
        int u = __shfl_up(v, m, 64);
        if (t >= m) v += u;
    }
    int ex = __shfl_up(v, 1, 64);
    if (t == 0) ex = 0;
    if (t < NBLK_SCAN) partials[t] = ex;
}

__global__ __launch_bounds__(256) void scanC_kernel(int* __restrict__ cursor,
                                                    const int* __restrict__ partials) {
    const int t = threadIdx.x;
    const int lane = t & 63, w = t >> 6;
    const int base = blockIdx.x * SCAN_CH + t * 8;
    int vals[8];
    int s = 0;
#pragma unroll
    for (int i = 0; i < 8; ++i) {
        int idx = base + i;
        vals[i] = (idx < NN) ? cursor[idx] : 0;
        s += vals[i];
    }
    int incl = s;
#pragma unroll
    for (int m = 1; m < 64; m <<= 1) {
        int u = __shfl_up(incl, m, 64);
        if (lane >= m) incl += u;
    }
    __shared__ int wsum[4];
    if (lane == 63) wsum[w] = incl;
    __syncthreads();
    int woff = partials[blockIdx.x];
    for (int i = 0; i < w; ++i) woff += wsum[i];
    int ex = incl - s + woff;
#pragma unroll
    for (int i = 0; i < 8; ++i) {
        int idx = base + i;
        if (idx < NN) cursor[idx] = ex;
        ex += vals[i];
        if (idx == NN - 1) cursor[NN] = ex;   // total = E
    }
}

// coarse_cursor[b] = CSR start of node b*BNODES (running cursor for P1)
__global__ void coarse_init_kernel(const int* __restrict__ cursor,
                                   int* __restrict__ coarse_cursor) {
    int t = threadIdx.x;            // 256 threads
    int g = t * BNODES;
    if (g > NN) g = NN;
    coarse_cursor[t] = cursor[g];
}

// P1: partition edges into 256 coarse buckets, contiguous group writes.
__global__ __launch_bounds__(256) void part_kernel(const void* __restrict__ ei,
                                                   int* __restrict__ coarse_cursor,
                                                   int2* __restrict__ pairs,
                                                   int E, const int* __restrict__ flag) {
    __shared__ int hist[NBUCK];
    __shared__ int blkoff[NBUCK];
    const int t = threadIdx.x;
    hist[t] = 0;
    __syncthreads();
    const int is64 = *flag;
    const long long base = (long long)blockIdx.x * P1_CH;

    int srcv[8], dstv[8], bkt[8], rnk[8];
#pragma unroll
    for (int i = 0; i < 8; ++i) {
        long long e = base + i * 256 + t;
        if (e < E) {
            srcv[i] = (int)load_idx(ei, e, is64);
            dstv[i] = (int)load_idx(ei, (long long)E + e, is64);
            bkt[i]  = (int)((unsigned)dstv[i] / BNODES);
            rnk[i]  = atomicAdd(&hist[bkt[i]], 1);
        } else {
            bkt[i] = -1;
        }
    }
    __syncthreads();
    blkoff[t] = atomicAdd(&coarse_cursor[t], hist[t]);
    __syncthreads();
#pragma unroll
    for (int i = 0; i < 8; ++i) {
        if (bkt[i] >= 0) {
            int pos = blkoff[bkt[i]] + rnk[i];
            pairs[pos] = make_int2(srcv[i], dstv[i]);
        }
    }
}

// P2: one block per coarse bucket; fine-place src into final CSR slots.
__global__ __launch_bounds__(256) void place_kernel(const int2* __restrict__ pairs,
                                                    const int* __restrict__ cursor,
                                                    int* __restrict__ bucket) {
    __shared__ int nstart[BNODES + 1];
    __shared__ int cnt[BNODES];
    const int b = blockIdx.x, t = threadIdx.x;
    const int g0 = b * BNODES;
    for (int j = t; j <= BNODES; j += 256) {
        int g = g0 + j;
        if (g > NN) g = NN;
        nstart[j] = cursor[g];
    }
    for (int j = t; j < BNODES; j += 256) cnt[j] = 0;
    __syncthreads();
    const int lo = nstart[0], hi = nstart[BNODES];
    for (int i = lo + t; i < hi; i += 256) {
        int2 p = pairs[i];
        int local = p.y - g0;
        int r = atomicAdd(&cnt[local], 1);
        bucket[nstart[local] + r] = p.x;
    }
}

// one wave per node: pull-sum incoming messages, add self-loop + bias, leaky.
__global__ __launch_bounds__(256) void gather_kernel(const float* __restrict__ h,
                                                     const float* __restrict__ dinv,
                                                     const int* __restrict__ cursor,
                                                     const int* __restrict__ bucket,
                                                     const float* __restrict__ b_conv,
                                                     float* __restrict__ ne) {
    const int node = blockIdx.x * 4 + (threadIdx.x >> 6);
    if (node >= NN) return;
    const int lane = threadIdx.x & 63;
    const int sub = lane & 15;
    const int eg = lane >> 4;

    const int base = cursor[node];
    const int end  = cursor[node + 1];
    const float dd = dinv[node];

    float4 acc = make_float4(0.f, 0.f, 0.f, 0.f);
    for (int k = base + eg; k < end; k += 4) {
        int s = bucket[k];
        float nrm = dinv[s] * dd;
        float4 hv = *(const float4*)(h + (long long)s * FH + sub * 4);
        acc.x += hv.x * nrm; acc.y += hv.y * nrm;
        acc.z += hv.z * nrm; acc.w += hv.w * nrm;
    }
#pragma unroll
    for (int m = 16; m < 64; m <<= 1) {
        acc.x += __shfl_xor(acc.x, m);
        acc.y += __shfl_xor(acc.y, m);
        acc.z += __shfl_xor(acc.z, m);
        acc.w += __shfl_xor(acc.w, m);
    }
    if (eg == 0) {
        float4 hv = *(const float4*)(h + (long long)node * FH + sub * 4);
        float4 bc = *(const float4*)(b_conv + sub * 4);
        float4 r;
        r.x = acc.x + hv.x * dd * dd + bc.x;
        r.y = acc.y + hv.y * dd * dd + bc.y;
        r.z = acc.z + hv.z * dd * dd + bc.z;
        r.w = acc.w + hv.w * dd * dd + bc.w;
        r.x = r.x >= 0.f ? r.x : NEG * r.x;
        r.y = r.y >= 0.f ? r.y : NEG * r.y;
        r.z = r.z >= 0.f ? r.z : NEG * r.z;
        r.w = r.w >= 0.f ? r.w : NEG * r.w;
        *(float4*)(ne + (long long)node * FH + sub * 4) = r;
    }
}

// ------------------------- fallback (round-1) path --------------------------

__global__ __launch_bounds__(256) void init_kernel(float* __restrict__ ne,
                                                   float* __restrict__ deg,
                                                   const float* __restrict__ b_conv) {
    int idx = blockIdx.x * 256 + threadIdx.x;
    if (idx < NN * FH) ne[idx] = b_conv[idx & (FH - 1)];
    if (idx < NN) deg[idx] = 1.0f;
}

__global__ __launch_bounds__(256) void deg_kernel(const void* __restrict__ ei,
                                                  float* __restrict__ deg,
                                                  int E, const int* __restrict__ flag) {
    int e = blockIdx.x * 256 + threadIdx.x;
    if (e >= E) return;
    long long d = load_idx(ei, (long long)E + e, *flag);
    atomicAdd(&deg[d], 1.0f);
}

__global__ __launch_bounds__(256) void rsqrt_kernel(float* __restrict__ deg) {
    int i = blockIdx.x * 256 + threadIdx.x;
    if (i < NN) deg[i] = rsqrtf(deg[i]);
}

__global__ __launch_bounds__(256) void selfloop_kernel(const float* __restrict__ h,
                                                       const float* __restrict__ dinv,
                                                       float* __restrict__ ne) {
    int idx = blockIdx.x * 256 + threadIdx.x;
    if (idx >= NN * FH) return;
    int i = idx >> 6;
    float di = dinv[i];
    ne[idx] += h[idx] * di * di;
}

__global__ __launch_bounds__(256) void edge_agg_kernel(const void* __restrict__ ei,
                                                       const float* __restrict__ dinv,
                                                       const float* __restrict__ h,
                                                       float* __restrict__ ne,
                                                       int E, const int* __restrict__ flag) {
    long long t = (long long)blockIdx.x * 256 + threadIdx.x;
    long long e = t >> 4;
    int sub = (int)(t & 15);
    if (e >= E) return;
    int is64 = *flag;
    long long s = load_idx(ei, e, is64);
    long long d = load_idx(ei, (long long)E + e, is64);
    float nrm = dinv[s] * dinv[d];
    float4 hv = *(const float4*)(h + s * FH + sub * 4);
    float* np_ = ne + d * FH + sub * 4;
    atomicAdd(np_ + 0, hv.x * nrm);
    atomicAdd(np_ + 1, hv.y * nrm);
    atomicAdd(np_ + 2, hv.z * nrm);
    atomicAdd(np_ + 3, hv.w * nrm);
}

// ------------------------- MLP head -----------------------------------------
__global__ __launch_bounds__(256) void mlp_kernel(const float* __restrict__ ne,
                                                  const void* __restrict__ idx,
                                                  const float* __restrict__ W1,
                                                  const float* __restrict__ b1,
                                                  const float* __restrict__ W2,
                                                  const float* __restrict__ b2,
                                                  float* __restrict__ out,
                                                  int B, const int* __restrict__ flag,
                                                  int pre_act) {
    const int lane = threadIdx.x & 63;
    const int wid = threadIdx.x >> 6;

    float w1a[16], w1b[16], b1r[16], w2r[16];
#pragma unroll
    for (int o = 0; o < 16; ++o) {
        w1a[o] = W1[lane * 16 + o];
        w1b[o] = W1[(64 + lane) * 16 + o];
        b1r[o] = b1[o];
        w2r[o] = W2[o];
    }
    const float b2v = b2[0];
    const int is64 = *flag;

    for (int pair = blockIdx.x * 4 + wid; pair < B; pair += gridDim.x * 4) {
        long long i0 = load_idx(idx, 2LL * pair, is64);
        long long i1 = load_idx(idx, 2LL * pair + 1, is64);
        float a = ne[i0 * FH + lane];
        float b = ne[i1 * FH + lane];
        if (pre_act) {
            a = a >= 0.f ? a : NEG * a;
            b = b >= 0.f ? b : NEG * b;
        }

        float acc[16];
#pragma unroll
        for (int o = 0; o < 16; ++o) acc[o] = a * w1a[o] + b * w1b[o];
#pragma unroll
        for (int m = 1; m < 64; m <<= 1) {
#pragma unroll
            for (int o = 0; o < 16; ++o) acc[o] += __shfl_xor(acc[o], m, 64);
        }
        if (lane == 0) {
            float s = b2v;
#pragma unroll
            for (int o = 0; o < 16; ++o) {
                float z = acc[o] + b1r[o];
                z = z >= 0.f ? z : NEG * z;
                s += z * w2r[o];
            }
            out[pair] = 1.f / (1.f + expf(-s));
        }
    }
}

extern "C" void kernel_launch(void* const* d_in, const int* in_sizes, int n_in,
                              void* d_out, int out_size, void* d_ws, size_t ws_size,
                              hipStream_t stream) {
    const float* x      = (const float*)d_in[0];
    const void*  ei     = d_in[1];
    const void*  index  = d_in[2];
    const float* W_conv = (const float*)d_in[3];
    const float* b_conv = (const float*)d_in[4];
    const float* W1     = (const float*)d_in[5];
    const float* b1     = (const float*)d_in[6];
    const float* W2     = (const float*)d_in[7];
    const float* b2     = (const float*)d_in[8];
    float* out = (float*)d_out;

    const int E = in_sizes[1] / 2;   // 1.6M
    const int B = in_sizes[2] / 2;   // 16384

    float* h  = (float*)d_ws;
    float* ne = h + (long long)NN * FH;

    const size_t need_new = ((size_t)2 * NN * FH + NN + (NN + 1) + (size_t)E
                             + 1 + NBLK_SCAN + NBUCK) * 4;

    if (ws_size >= need_new) {
        // CSR pull path with two-level counting sort
        float* dinv     = ne + (long long)NN * FH;
        int*   cursor   = (int*)(dinv + NN);          // NN+1 entries
        int*   bucket   = cursor + (NN + 1);
        int*   flag     = bucket + E;
        int*   partials = flag + 1;
        int*   coarse_cursor = partials + NBLK_SCAN;
        int2*  pairs    = (int2*)ne;                  // staged in dead ne buffer

        detect_kernel<<<1, 64, 0, stream>>>((const int*)ei, flag);
        zero_kernel<<<(NN + 255) / 256, 256, 0, stream>>>(cursor);
        gemm_kernel<<<2048, 256, 0, stream>>>(x, W_conv, h);
        count_kernel<<<(E + 255) / 256, 256, 0, stream>>>(ei, cursor, E, flag);
        dinv_kernel<<<(NN + 255) / 256, 256, 0, stream>>>(cursor, dinv);
        scanA_kernel<<<NBLK_SCAN, 256, 0, stream>>>(cursor, partials);
        scanB_kernel<<<1, 64, 0, stream>>>(partials);
        scanC_kernel<<<NBLK_SCAN, 256, 0, stream>>>(cursor, partials);
        coarse_init_kernel<<<1, NBUCK, 0, stream>>>(cursor, coarse_cursor);
        part_kernel<<<(E + P1_CH - 1) / P1_CH, 256, 0, stream>>>(ei, coarse_cursor, pairs, E, flag);
        place_kernel<<<NBUCK, 256, 0, stream>>>(pairs, cursor, bucket);
        gather_kernel<<<(NN + 3) / 4, 256, 0, stream>>>(h, dinv, cursor, bucket, b_conv, ne);
        mlp_kernel<<<512, 256, 0, stream>>>(ne, index, W1, b1, W2, b2, out, B, flag, 0);
    } else {
        // fallback: round-1 atomic scatter
        float* deg = ne + (long long)NN * FH;
        int* flag  = (int*)(deg + NN);

        detect_kernel<<<1, 64, 0, stream>>>((const int*)ei, flag);
        init_kernel<<<(NN * FH + 255) / 256, 256, 0, stream>>>(ne, deg, b_conv);
        gemm_kernel<<<2048, 256, 0, stream>>>(x, W_conv, h);
        deg_kernel<<<(E + 255) / 256, 256, 0, stream>>>(ei, deg, E, flag);
        rsqrt_kernel<<<(NN + 255) / 256, 256, 0, stream>>>(deg);
        selfloop_kernel<<<(NN * FH + 255) / 256, 256, 0, stream>>>(h, deg, ne);
        edge_agg_kernel<<<(int)(((long long)E * 16 + 255) / 256), 256, 0, stream>>>(ei, deg, h, ne, E, flag);
        mlp_kernel<<<512, 256, 0, stream>>>(ne, index, W1, b1, W2, b2, out, B, flag, 1);
    }
}

// Round 5
// 239.661 us; speedup vs baseline: 6.5279x; 1.1904x over previous
//
#include <hip/hip_runtime.h>
#include <hip/hip_bf16.h>

#define NN 100000      // nodes
#define FIN 256        // input features
#define FH 64          // hidden features
#define NEG 0.01f
#define SCAN_CH 2048
#define NBLK_SCAN ((NN + SCAN_CH - 1) / SCAN_CH)   // 49
#define NBUCK 256
#define BNODES ((NN + NBUCK - 1) / NBUCK)          // 391 nodes per coarse bucket
#define P1_CH 2048
#define WP 264         // LDS pitch for W^T (bf16 elems): 2-way bank conflict only

typedef __attribute__((ext_vector_type(8))) short short8x;
typedef __attribute__((ext_vector_type(4))) float f32x4;

__device__ inline unsigned short f2bf(float f) {
    unsigned u = __float_as_uint(f);
    u = (u + 0x7FFF + ((u >> 16) & 1)) >> 16;   // RNE
    return (unsigned short)u;
}
__device__ inline float bf2f(unsigned short s) {
    return __uint_as_float(((unsigned)s) << 16);
}

// ---------------------------------------------------------------------------
// ws layout (CSR path), bytes:
//   hbf[NN*FH] (bf16) | ne[NN*FH] f32 (pairs int2[E] staged here pre-gather) |
//   dinv[NN] | cursor[NN+1] | bucket[E] | flag | partials[NBLK_SCAN] | coarse[NBUCK]
// Fallback (ws too small): h f32 | ne | deg | flag  (round-1 atomic scatter)
// ---------------------------------------------------------------------------

__global__ void detect_kernel(const int* __restrict__ ei32, int* __restrict__ flag) {
    if (blockIdx.x == 0 && threadIdx.x == 0) {
        int ok = 1;
        for (int k = 0; k < 64; ++k)
            if (ei32[2 * k + 1] != 0) { ok = 0; break; }
        *flag = ok;   // 1 => int64, 0 => int32
    }
}

__device__ inline long long load_idx(const void* p, long long i, int is64) {
    if (is64) return ((const long long*)p)[i];
    return (long long)((const int*)p)[i];
}

// ---------------- bf16 MFMA GEMM: hbf = bf16( x @ W_conv ) ------------------
// block = 4 waves, 64 rows (16/wave). W^T staged in LDS as bf16 once per block.
__global__ __launch_bounds__(256) void gemm_bf16_kernel(const float* __restrict__ x,
                                                        const float* __restrict__ W,
                                                        unsigned short* __restrict__ hbf) {
    __shared__ unsigned short Wt[FH * WP];   // [col][k], pitch WP

    // stage W (256x64 f32) -> Wt bf16 transposed; coalesced reads
    for (int i = threadIdx.x; i < FIN * FH; i += 256) {
        int k = i >> 6, c = i & 63;
        Wt[c * WP + k] = f2bf(W[i]);
    }
    __syncthreads();

    const int wv = threadIdx.x >> 6;
    const int lane = threadIdx.x & 63;
    const int c = lane & 15;          // A-row / B-col / D-col index
    const int eg = lane >> 4;         // k-group

    const int row0 = (blockIdx.x * 4 + wv) * 16;
    int rowA = row0 + c;
    if (rowA >= NN) rowA = NN - 1;            // clamped load; store guarded
    const float* aptr = x + (long long)rowA * FIN;

    f32x4 acc[4] = {{0,0,0,0},{0,0,0,0},{0,0,0,0},{0,0,0,0}};

#pragma unroll
    for (int kk = 0; kk < 8; ++kk) {
        const int kbase = kk * 32 + eg * 8;
        float4 f0 = *(const float4*)(aptr + kbase);
        float4 f1 = *(const float4*)(aptr + kbase + 4);
        short8x a;
        a[0] = (short)f2bf(f0.x); a[1] = (short)f2bf(f0.y);
        a[2] = (short)f2bf(f0.z); a[3] = (short)f2bf(f0.w);
        a[4] = (short)f2bf(f1.x); a[5] = (short)f2bf(f1.y);
        a[6] = (short)f2bf(f1.z); a[7] = (short)f2bf(f1.w);
#pragma unroll
        for (int cb = 0; cb < 4; ++cb) {
            short8x b = *(const short8x*)(&Wt[(cb * 16 + c) * WP + kbase]);
            acc[cb] = __builtin_amdgcn_mfma_f32_16x16x32_bf16(a, b, acc[cb], 0, 0, 0);
        }
    }

#pragma unroll
    for (int cb = 0; cb < 4; ++cb) {
#pragma unroll
        for (int r = 0; r < 4; ++r) {
            int rowO = row0 + eg * 4 + r;     // D: row = 4*(lane>>4)+reg
            if (rowO < NN)
                hbf[(long long)rowO * FH + cb * 16 + c] = f2bf(acc[cb][r]);
        }
    }
}

// ------------------------- CSR pull path -----------------------------------

__global__ __launch_bounds__(256) void zero_kernel(int* __restrict__ cursor) {
    int i = blockIdx.x * 256 + threadIdx.x;
    if (i < NN) cursor[i] = 0;
}

__global__ __launch_bounds__(256) void count_kernel(const void* __restrict__ ei,
                                                    int* __restrict__ cursor,
                                                    int E, const int* __restrict__ flag) {
    int e = blockIdx.x * 256 + threadIdx.x;
    if (e >= E) return;
    long long d = load_idx(ei, (long long)E + e, *flag);
    atomicAdd(&cursor[d], 1);
}

__global__ __launch_bounds__(256) void dinv_kernel(const int* __restrict__ cursor,
                                                   float* __restrict__ dinv) {
    int i = blockIdx.x * 256 + threadIdx.x;
    if (i < NN) dinv[i] = rsqrtf(1.0f + (float)cursor[i]);
}

// ---- 3-phase exclusive scan of cursor[NN]; scanC also writes cursor[NN]=E ----
__global__ __launch_bounds__(256) void scanA_kernel(const int* __restrict__ cursor,
                                                    int* __restrict__ partials) {
    const int t = threadIdx.x;
    const int base = blockIdx.x * SCAN_CH + t * 8;
    int s = 0;
#pragma unroll
    for (int i = 0; i < 8; ++i) {
        int idx = base + i;
        if (idx < NN) s += cursor[idx];
    }
#pragma unroll
    for (int m = 1; m < 64; m <<= 1) s += __shfl_xor(s, m, 64);
    __shared__ int ws[4];
    if ((t & 63) == 0) ws[t >> 6] = s;
    __syncthreads();
    if (t == 0) partials[blockIdx.x] = ws[0] + ws[1] + ws[2] + ws[3];
}

__global__ __launch_bounds__(64) void scanB_kernel(int* __restrict__ partials) {
    const int t = threadIdx.x;
    int v = (t < NBLK_SCAN) ? partials[t] : 0;
#pragma unroll
    for (int m = 1; m < 64; m <<= 1) {
        int u = __shfl_up(v, m, 64);
        if (t >= m) v += u;
    }
    int ex = __shfl_up(v, 1, 64);
    if (t == 0) ex = 0;
    if (t < NBLK_SCAN) partials[t] = ex;
}

__global__ __launch_bounds__(256) void scanC_kernel(int* __restrict__ cursor,
                                                    const int* __restrict__ partials) {
    const int t = threadIdx.x;
    const int lane = t & 63, w = t >> 6;
    const int base = blockIdx.x * SCAN_CH + t * 8;
    int vals[8];
    int s = 0;
#pragma unroll
    for (int i = 0; i < 8; ++i) {
        int idx = base + i;
        vals[i] = (idx < NN) ? cursor[idx] : 0;
        s += vals[i];
    }
    int incl = s;
#pragma unroll
    for (int m = 1; m < 64; m <<= 1) {
        int u = __shfl_up(incl, m, 64);
        if (lane >= m) incl += u;
    }
    __shared__ int wsum[4];
    if (lane == 63) wsum[w] = incl;
    __syncthreads();
    int woff = partials[blockIdx.x];
    for (int i = 0; i < w; ++i) woff += wsum[i];
    int ex = incl - s + woff;
#pragma unroll
    for (int i = 0; i < 8; ++i) {
        int idx = base + i;
        if (idx < NN) cursor[idx] = ex;
        ex += vals[i];
        if (idx == NN - 1) cursor[NN] = ex;   // total = E
    }
}

__global__ void coarse_init_kernel(const int* __restrict__ cursor,
                                   int* __restrict__ coarse_cursor) {
    int t = threadIdx.x;            // 256 threads
    int g = t * BNODES;
    if (g > NN) g = NN;
    coarse_cursor[t] = cursor[g];
}

// P1: partition edges into 256 coarse buckets, contiguous group writes.
__global__ __launch_bounds__(256) void part_kernel(const void* __restrict__ ei,
                                                   int* __restrict__ coarse_cursor,
                                                   int2* __restrict__ pairs,
                                                   int E, const int* __restrict__ flag) {
    __shared__ int hist[NBUCK];
    __shared__ int blkoff[NBUCK];
    const int t = threadIdx.x;
    hist[t] = 0;
    __syncthreads();
    const int is64 = *flag;
    const long long base = (long long)blockIdx.x * P1_CH;

    int srcv[8], dstv[8], bkt[8], rnk[8];
#pragma unroll
    for (int i = 0; i < 8; ++i) {
        long long e = base + i * 256 + t;
        if (e < E) {
            srcv[i] = (int)load_idx(ei, e, is64);
            dstv[i] = (int)load_idx(ei, (long long)E + e, is64);
            bkt[i]  = (int)((unsigned)dstv[i] / BNODES);
            rnk[i]  = atomicAdd(&hist[bkt[i]], 1);
        } else {
            bkt[i] = -1;
        }
    }
    __syncthreads();
    blkoff[t] = atomicAdd(&coarse_cursor[t], hist[t]);
    __syncthreads();
#pragma unroll
    for (int i = 0; i < 8; ++i) {
        if (bkt[i] >= 0) {
            int pos = blkoff[bkt[i]] + rnk[i];
            pairs[pos] = make_int2(srcv[i], dstv[i]);
        }
    }
}

// P2: one block per coarse bucket; fine-place src into final CSR slots.
__global__ __launch_bounds__(256) void place_kernel(const int2* __restrict__ pairs,
                                                    const int* __restrict__ cursor,
                                                    int* __restrict__ bucket) {
    __shared__ int nstart[BNODES + 1];
    __shared__ int cnt[BNODES];
    const int b = blockIdx.x, t = threadIdx.x;
    const int g0 = b * BNODES;
    for (int j = t; j <= BNODES; j += 256) {
        int g = g0 + j;
        if (g > NN) g = NN;
        nstart[j] = cursor[g];
    }
    for (int j = t; j < BNODES; j += 256) cnt[j] = 0;
    __syncthreads();
    const int lo = nstart[0], hi = nstart[BNODES];
    for (int i = lo + t; i < hi; i += 256) {
        int2 p = pairs[i];
        int local = p.y - g0;
        int r = atomicAdd(&cnt[local], 1);
        bucket[nstart[local] + r] = p.x;
    }
}

// one wave per node, 8 edges in flight: pull-sum, self-loop + bias, leaky.
__global__ __launch_bounds__(256) void gather8_kernel(const unsigned short* __restrict__ hbf,
                                                      const float* __restrict__ dinv,
                                                      const int* __restrict__ cursor,
                                                      const int* __restrict__ bucket,
                                                      const float* __restrict__ b_conv,
                                                      float* __restrict__ ne) {
    const int node = blockIdx.x * 4 + (threadIdx.x >> 6);
    if (node >= NN) return;
    const int lane = threadIdx.x & 63;
    const int sub = lane & 7;     // 8-bf16 chunk of the row
    const int eg = lane >> 3;     // edge slot (8)

    const int base = cursor[node];
    const int end  = cursor[node + 1];
    const float dd = dinv[node];

    float acc[8] = {0,0,0,0,0,0,0,0};
    for (int k = base + eg; k < end; k += 8) {
        int s = bucket[k];
        float nrm = dinv[s] * dd;
        short8x hv = *(const short8x*)(hbf + (long long)s * FH + sub * 8);
#pragma unroll
        for (int j = 0; j < 8; ++j)
            acc[j] += bf2f((unsigned short)hv[j]) * nrm;
    }
#pragma unroll
    for (int m = 8; m < 64; m <<= 1) {
#pragma unroll
        for (int j = 0; j < 8; ++j) acc[j] += __shfl_xor(acc[j], m);
    }
    if (eg == 0) {
        short8x hs = *(const short8x*)(hbf + (long long)node * FH + sub * 8);
        float r[8];
#pragma unroll
        for (int j = 0; j < 8; ++j) {
            float v = acc[j] + bf2f((unsigned short)hs[j]) * dd * dd + b_conv[sub * 8 + j];
            r[j] = v >= 0.f ? v : NEG * v;
        }
        float4* o = (float4*)(ne + (long long)node * FH + sub * 8);
        o[0] = make_float4(r[0], r[1], r[2], r[3]);
        o[1] = make_float4(r[4], r[5], r[6], r[7]);
    }
}

// ------------------------- fallback (round-1) path --------------------------

__global__ __launch_bounds__(256) void gemm_kernel(const float* __restrict__ x,
                                                   const float* __restrict__ W,
                                                   float* __restrict__ h) {
    __shared__ float xs[4 * FIN];
    __shared__ float part[4][4][FH];

    const int col = threadIdx.x & 63;
    const int kseg = threadIdx.x >> 6;

    float wreg[64];
#pragma unroll
    for (int kk = 0; kk < 64; ++kk)
        wreg[kk] = W[(kseg * 64 + kk) * FH + col];

    for (int row0 = blockIdx.x * 4; row0 < NN; row0 += gridDim.x * 4) {
        const float4* xv = (const float4*)(x + (long long)row0 * FIN);
        ((float4*)xs)[threadIdx.x] = xv[threadIdx.x];
        __syncthreads();

        float acc[4] = {0.f, 0.f, 0.f, 0.f};
#pragma unroll
        for (int kk = 0; kk < 64; ++kk) {
            const float w = wreg[kk];
            const int k = kseg * 64 + kk;
#pragma unroll
            for (int r = 0; r < 4; ++r)
                acc[r] += xs[r * FIN + k] * w;
        }
#pragma unroll
        for (int r = 0; r < 4; ++r) part[r][kseg][col] = acc[r];
        __syncthreads();

        const int row = threadIdx.x >> 6;
        float s = part[row][0][col] + part[row][1][col] + part[row][2][col] + part[row][3][col];
        h[(long long)(row0 + row) * FH + col] = s;
        __syncthreads();
    }
}

__global__ __launch_bounds__(256) void init_kernel(float* __restrict__ ne,
                                                   float* __restrict__ deg,
                                                   const float* __restrict__ b_conv) {
    int idx = blockIdx.x * 256 + threadIdx.x;
    if (idx < NN * FH) ne[idx] = b_conv[idx & (FH - 1)];
    if (idx < NN) deg[idx] = 1.0f;
}

__global__ __launch_bounds__(256) void deg_kernel(const void* __restrict__ ei,
                                                  float* __restrict__ deg,
                                                  int E, const int* __restrict__ flag) {
    int e = blockIdx.x * 256 + threadIdx.x;
    if (e >= E) return;
    long long d = load_idx(ei, (long long)E + e, *flag);
    atomicAdd(&deg[d], 1.0f);
}

__global__ __launch_bounds__(256) void rsqrt_kernel(float* __restrict__ deg) {
    int i = blockIdx.x * 256 + threadIdx.x;
    if (i < NN) deg[i] = rsqrtf(deg[i]);
}

__global__ __launch_bounds__(256) void selfloop_kernel(const float* __restrict__ h,
                                                       const float* __restrict__ dinv,
                                                       float* __restrict__ ne) {
    int idx = blockIdx.x * 256 + threadIdx.x;
    if (idx >= NN * FH) return;
    int i = idx >> 6;
    float di = dinv[i];
    ne[idx] += h[idx] * di * di;
}

__global__ __launch_bounds__(256) void edge_agg_kernel(const void* __restrict__ ei,
                                                       const float* __restrict__ dinv,
                                                       const float* __restrict__ h,
                                                       float* __restrict__ ne,
                                                       int E, const int* __restrict__ flag) {
    long long t = (long long)blockIdx.x * 256 + threadIdx.x;
    long long e = t >> 4;
    int sub = (int)(t & 15);
    if (e >= E) return;
    int is64 = *flag;
    long long s = load_idx(ei, e, is64);
    long long d = load_idx(ei, (long long)E + e, is64);
    float nrm = dinv[s] * dinv[d];
    float4 hv = *(const float4*)(h + s * FH + sub * 4);
    float* np_ = ne + d * FH + sub * 4;
    atomicAdd(np_ + 0, hv.x * nrm);
    atomicAdd(np_ + 1, hv.y * nrm);
    atomicAdd(np_ + 2, hv.z * nrm);
    atomicAdd(np_ + 3, hv.w * nrm);
}

// ------------------------- MLP head -----------------------------------------
__global__ __launch_bounds__(256) void mlp_kernel(const float* __restrict__ ne,
                                                  const void* __restrict__ idx,
                                                  const float* __restrict__ W1,
                                                  const float* __restrict__ b1,
                                                  const float* __restrict__ W2,
                                                  const float* __restrict__ b2,
                                                  float* __restrict__ out,
                                                  int B, const int* __restrict__ flag,
                                                  int pre_act) {
    const int lane = threadIdx.x & 63;
    const int wid = threadIdx.x >> 6;

    float w1a[16], w1b[16], b1r[16], w2r[16];
#pragma unroll
    for (int o = 0; o < 16; ++o) {
        w1a[o] = W1[lane * 16 + o];
        w1b[o] = W1[(64 + lane) * 16 + o];
        b1r[o] = b1[o];
        w2r[o] = W2[o];
    }
    const float b2v = b2[0];
    const int is64 = *flag;

    for (int pair = blockIdx.x * 4 + wid; pair < B; pair += gridDim.x * 4) {
        long long i0 = load_idx(idx, 2LL * pair, is64);
        long long i1 = load_idx(idx, 2LL * pair + 1, is64);
        float a = ne[i0 * FH + lane];
        float b = ne[i1 * FH + lane];
        if (pre_act) {
            a = a >= 0.f ? a : NEG * a;
            b = b >= 0.f ? b : NEG * b;
        }

        float acc[16];
#pragma unroll
        for (int o = 0; o < 16; ++o) acc[o] = a * w1a[o] + b * w1b[o];
#pragma unroll
        for (int m = 1; m < 64; m <<= 1) {
#pragma unroll
            for (int o = 0; o < 16; ++o) acc[o] += __shfl_xor(acc[o], m, 64);
        }
        if (lane == 0) {
            float s = b2v;
#pragma unroll
            for (int o = 0; o < 16; ++o) {
                float z = acc[o] + b1r[o];
                z = z >= 0.f ? z : NEG * z;
                s += z * w2r[o];
            }
            out[pair] = 1.f / (1.f + expf(-s));
        }
    }
}

extern "C" void kernel_launch(void* const* d_in, const int* in_sizes, int n_in,
                              void* d_out, int out_size, void* d_ws, size_t ws_size,
                              hipStream_t stream) {
    const float* x      = (const float*)d_in[0];
    const void*  ei     = d_in[1];
    const void*  index  = d_in[2];
    const float* W_conv = (const float*)d_in[3];
    const float* b_conv = (const float*)d_in[4];
    const float* W1     = (const float*)d_in[5];
    const float* b1     = (const float*)d_in[6];
    const float* W2     = (const float*)d_in[7];
    const float* b2     = (const float*)d_in[8];
    float* out = (float*)d_out;

    const int E = in_sizes[1] / 2;   // 1.6M
    const int B = in_sizes[2] / 2;   // 16384

    const size_t need_new = (size_t)NN * FH * 2
                          + ((size_t)NN * FH + NN + (NN + 1) + (size_t)E
                             + 1 + NBLK_SCAN + NBUCK) * 4;

    if (ws_size >= need_new) {
        // CSR pull path, bf16 h
        unsigned short* hbf = (unsigned short*)d_ws;
        float* ne       = (float*)(hbf + (long long)NN * FH);
        float* dinv     = ne + (long long)NN * FH;
        int*   cursor   = (int*)(dinv + NN);          // NN+1 entries
        int*   bucket   = cursor + (NN + 1);
        int*   flag     = bucket + E;
        int*   partials = flag + 1;
        int*   coarse_cursor = partials + NBLK_SCAN;
        int2*  pairs    = (int2*)ne;                  // staged in dead ne buffer

        detect_kernel<<<1, 64, 0, stream>>>((const int*)ei, flag);
        zero_kernel<<<(NN + 255) / 256, 256, 0, stream>>>(cursor);
        gemm_bf16_kernel<<<(NN + 63) / 64, 256, 0, stream>>>(x, W_conv, hbf);
        count_kernel<<<(E + 255) / 256, 256, 0, stream>>>(ei, cursor, E, flag);
        dinv_kernel<<<(NN + 255) / 256, 256, 0, stream>>>(cursor, dinv);
        scanA_kernel<<<NBLK_SCAN, 256, 0, stream>>>(cursor, partials);
        scanB_kernel<<<1, 64, 0, stream>>>(partials);
        scanC_kernel<<<NBLK_SCAN, 256, 0, stream>>>(cursor, partials);
        coarse_init_kernel<<<1, NBUCK, 0, stream>>>(cursor, coarse_cursor);
        part_kernel<<<(E + P1_CH - 1) / P1_CH, 256, 0, stream>>>(ei, coarse_cursor, pairs, E, flag);
        place_kernel<<<NBUCK, 256, 0, stream>>>(pairs, cursor, bucket);
        gather8_kernel<<<(NN + 3) / 4, 256, 0, stream>>>(hbf, dinv, cursor, bucket, b_conv, ne);
        mlp_kernel<<<512, 256, 0, stream>>>(ne, index, W1, b1, W2, b2, out, B, flag, 0);
    } else {
        // fallback: round-1 atomic scatter (fp32)
        float* h   = (float*)d_ws;
        float* ne  = h + (long long)NN * FH;
        float* deg = ne + (long long)NN * FH;
        int* flag  = (int*)(deg + NN);

        detect_kernel<<<1, 64, 0, stream>>>((const int*)ei, flag);
        init_kernel<<<(NN * FH + 255) / 256, 256, 0, stream>>>(ne, deg, b_conv);
        gemm_kernel<<<2048, 256, 0, stream>>>(x, W_conv, h);
        deg_kernel<<<(E + 255) / 256, 256, 0, stream>>>(ei, deg, E, flag);
        rsqrt_kernel<<<(NN + 255) / 256, 256, 0, stream>>>(deg);
        selfloop_kernel<<<(NN * FH + 255) / 256, 256, 0, stream>>>(h, deg, ne);
        edge_agg_kernel<<<(int)(((long long)E * 16 + 255) / 256), 256, 0, stream>>>(ei, deg, h, ne, E, flag);
        mlp_kernel<<<512, 256, 0, stream>>>(ne, index, W1, b1, W2, b2, out, B, flag, 1);
    }
}

// Round 6
// 181.243 us; speedup vs baseline: 8.6319x; 1.3223x over previous
//
#include <hip/hip_runtime.h>
#include <hip/hip_bf16.h>

#define NN 100000      // nodes
#define FIN 256        // input features
#define FH 64          // hidden features
#define NEG 0.01f
#define NBUCK 256
#define BNODES ((NN + NBUCK - 1) / NBUCK)          // 391 nodes per coarse bucket
#define P1_CH 2048
#define WP 264         // LDS pitch for W^T (bf16 elems): 2-way bank conflict only

typedef __attribute__((ext_vector_type(8))) short short8x;
typedef __attribute__((ext_vector_type(4))) float f32x4;

__device__ inline unsigned short f2bf(float f) {
    unsigned u = __float_as_uint(f);
    u = (u + 0x7FFF + ((u >> 16) & 1)) >> 16;   // RNE
    return (unsigned short)u;
}
__device__ inline float bf2f(unsigned short s) {
    return __uint_as_float(((unsigned)s) << 16);
}

// ---------------------------------------------------------------------------
// ws layout (CSR path), bytes:
//   hbf[NN*FH] bf16 | ne[NN*FH] f32 (pairs int2[E] staged here pre-gather) |
//   dinv[NN] | cursor[NN+1] | bucket[E] | flag | coarse_cnt[NBUCK] |
//   coarse[NBUCK+1] | coarse_cursor[NBUCK]
// Fallback (ws too small): h f32 | ne | deg | flag  (round-1 atomic scatter)
// ---------------------------------------------------------------------------

// flag detect + zero the coarse histogram (one block, 256 threads)
__global__ void detect_zero_kernel(const int* __restrict__ ei32, int* __restrict__ flag,
                                   int* __restrict__ coarse_cnt) {
    const int t = threadIdx.x;
    coarse_cnt[t] = 0;
    if (t == 0) {
        int ok = 1;
        for (int k = 0; k < 64; ++k)
            if (ei32[2 * k + 1] != 0) { ok = 0; break; }
        *flag = ok;   // 1 => int64, 0 => int32
    }
}

__device__ inline long long load_idx(const void* p, long long i, int is64) {
    if (is64) return ((const long long*)p)[i];
    return (long long)((const int*)p)[i];
}

// ---------------- bf16 MFMA GEMM: hbf = bf16( x @ W_conv ) ------------------
__global__ __launch_bounds__(256) void gemm_bf16_kernel(const float* __restrict__ x,
                                                        const float* __restrict__ W,
                                                        unsigned short* __restrict__ hbf) {
    __shared__ unsigned short Wt[FH * WP];   // [col][k], pitch WP

    for (int i = threadIdx.x; i < FIN * FH; i += 256) {
        int k = i >> 6, c = i & 63;
        Wt[c * WP + k] = f2bf(W[i]);
    }
    __syncthreads();

    const int wv = threadIdx.x >> 6;
    const int lane = threadIdx.x & 63;
    const int c = lane & 15;
    const int eg = lane >> 4;

    const int row0 = (blockIdx.x * 4 + wv) * 16;
    int rowA = row0 + c;
    if (rowA >= NN) rowA = NN - 1;
    const float* aptr = x + (long long)rowA * FIN;

    f32x4 acc[4] = {{0,0,0,0},{0,0,0,0},{0,0,0,0},{0,0,0,0}};

#pragma unroll
    for (int kk = 0; kk < 8; ++kk) {
        const int kbase = kk * 32 + eg * 8;
        float4 f0 = *(const float4*)(aptr + kbase);
        float4 f1 = *(const float4*)(aptr + kbase + 4);
        short8x a;
        a[0] = (short)f2bf(f0.x); a[1] = (short)f2bf(f0.y);
        a[2] = (short)f2bf(f0.z); a[3] = (short)f2bf(f0.w);
        a[4] = (short)f2bf(f1.x); a[5] = (short)f2bf(f1.y);
        a[6] = (short)f2bf(f1.z); a[7] = (short)f2bf(f1.w);
#pragma unroll
        for (int cb = 0; cb < 4; ++cb) {
            short8x b = *(const short8x*)(&Wt[(cb * 16 + c) * WP + kbase]);
            acc[cb] = __builtin_amdgcn_mfma_f32_16x16x32_bf16(a, b, acc[cb], 0, 0, 0);
        }
    }

#pragma unroll
    for (int cb = 0; cb < 4; ++cb) {
#pragma unroll
        for (int r = 0; r < 4; ++r) {
            int rowO = row0 + eg * 4 + r;
            if (rowO < NN)
                hbf[(long long)rowO * FH + cb * 16 + c] = f2bf(acc[cb][r]);
        }
    }
}

// ------------------------- CSR build (no per-node global atomics) -----------

// coarse histogram of dst/BNODES: 256 blocks, LDS hist, 256 global atomics/blk
__global__ __launch_bounds__(256) void coarse_count_kernel(const void* __restrict__ ei,
                                                           int* __restrict__ coarse_cnt,
                                                           int E, const int* __restrict__ flag) {
    __shared__ int hist[NBUCK];
    const int t = threadIdx.x;
    hist[t] = 0;
    __syncthreads();
    const int is64 = *flag;
    for (long long e = (long long)blockIdx.x * 256 + t; e < E; e += (long long)gridDim.x * 256) {
        int d = (int)load_idx(ei, (long long)E + e, is64);
        atomicAdd(&hist[(unsigned)d / BNODES], 1);
    }
    __syncthreads();
    if (hist[t]) atomicAdd(&coarse_cnt[t], hist[t]);
}

// exclusive scan of coarse_cnt[256] -> coarse[257], coarse_cursor[256]
__global__ __launch_bounds__(256) void coarse_scan_kernel(const int* __restrict__ coarse_cnt,
                                                          int* __restrict__ coarse,
                                                          int* __restrict__ coarse_cursor) {
    const int t = threadIdx.x;
    const int lane = t & 63, w = t >> 6;
    int v = coarse_cnt[t];
    int incl = v;
#pragma unroll
    for (int m = 1; m < 64; m <<= 1) {
        int u = __shfl_up(incl, m, 64);
        if (lane >= m) incl += u;
    }
    __shared__ int wsum[4];
    if (lane == 63) wsum[w] = incl;
    __syncthreads();
    int woff = 0;
    for (int i = 0; i < w; ++i) woff += wsum[i];
    int ex = woff + incl - v;
    coarse[t] = ex;
    coarse_cursor[t] = ex;
    if (t == 255) coarse[NBUCK] = ex + v;   // = E
}

// P1: partition edges into 256 coarse buckets, contiguous group writes.
__global__ __launch_bounds__(256) void part_kernel(const void* __restrict__ ei,
                                                   int* __restrict__ coarse_cursor,
                                                   int2* __restrict__ pairs,
                                                   int E, const int* __restrict__ flag) {
    __shared__ int hist[NBUCK];
    __shared__ int blkoff[NBUCK];
    const int t = threadIdx.x;
    hist[t] = 0;
    __syncthreads();
    const int is64 = *flag;
    const long long base = (long long)blockIdx.x * P1_CH;

    int srcv[8], dstv[8], bkt[8], rnk[8];
#pragma unroll
    for (int i = 0; i < 8; ++i) {
        long long e = base + i * 256 + t;
        if (e < E) {
            srcv[i] = (int)load_idx(ei, e, is64);
            dstv[i] = (int)load_idx(ei, (long long)E + e, is64);
            bkt[i]  = (int)((unsigned)dstv[i] / BNODES);
            rnk[i]  = atomicAdd(&hist[bkt[i]], 1);
        } else {
            bkt[i] = -1;
        }
    }
    __syncthreads();
    blkoff[t] = atomicAdd(&coarse_cursor[t], hist[t]);
    __syncthreads();
#pragma unroll
    for (int i = 0; i < 8; ++i) {
        if (bkt[i] >= 0) {
            int pos = blkoff[bkt[i]] + rnk[i];
            pairs[pos] = make_int2(srcv[i], dstv[i]);
        }
    }
}

// P2: per coarse bucket: LDS-count local degrees, LDS-scan, emit cursor+dinv,
// then place src into final CSR slots. No global atomics.
__global__ __launch_bounds__(256) void place2_kernel(const int2* __restrict__ pairs,
                                                     const int* __restrict__ coarse,
                                                     int* __restrict__ cursor,
                                                     float* __restrict__ dinv,
                                                     int* __restrict__ bucket) {
    __shared__ int cnt[BNODES];
    __shared__ int nstart[BNODES + 1];
    __shared__ int wsum[4];
    const int b = blockIdx.x, t = threadIdx.x;
    const int lane = t & 63, w = t >> 6;
    const int g0 = b * BNODES;
    const int nb = (NN - g0 < BNODES) ? (NN - g0) : BNODES;
    const int lo = coarse[b], hi = coarse[b + 1];

    for (int j = t; j < nb; j += 256) cnt[j] = 0;
    __syncthreads();

    // pass 1: local degree count
    for (int i = lo + t; i < hi; i += 256)
        atomicAdd(&cnt[pairs[i].y - g0], 1);
    __syncthreads();

    // exclusive scan of cnt[0..nb) -> nstart[0..nb]
    const int i0 = 2 * t, i1 = 2 * t + 1;
    const int v0 = (i0 < nb) ? cnt[i0] : 0;
    const int v1 = (i1 < nb) ? cnt[i1] : 0;
    const int s = v0 + v1;
    int incl = s;
#pragma unroll
    for (int m = 1; m < 64; m <<= 1) {
        int u = __shfl_up(incl, m, 64);
        if (lane >= m) incl += u;
    }
    if (lane == 63) wsum[w] = incl;
    __syncthreads();
    int woff = 0;
    for (int i = 0; i < w; ++i) woff += wsum[i];
    const int ex = woff + incl - s;
    if (i0 <= nb) nstart[i0] = ex;
    if (i1 <= nb) nstart[i1] = ex + v0;
    __syncthreads();

    // emit cursor + dinv (coalesced)
    for (int j = t; j <= nb; j += 256) {
        int g = g0 + j;
        if (g <= NN) cursor[g] = lo + nstart[j];
    }
    for (int j = t; j < nb; j += 256)
        dinv[g0 + j] = rsqrtf(1.0f + (float)(nstart[j + 1] - nstart[j]));

    // pass 2: place
    for (int j = t; j < nb; j += 256) cnt[j] = 0;
    __syncthreads();
    for (int i = lo + t; i < hi; i += 256) {
        int2 p = pairs[i];
        int local = p.y - g0;
        int r = atomicAdd(&cnt[local], 1);
        bucket[lo + nstart[local] + r] = p.x;
    }
}

// one wave per node, 8 edges in flight: pull-sum, self-loop + bias, leaky.
__global__ __launch_bounds__(256) void gather8_kernel(const unsigned short* __restrict__ hbf,
                                                      const float* __restrict__ dinv,
                                                      const int* __restrict__ cursor,
                                                      const int* __restrict__ bucket,
                                                      const float* __restrict__ b_conv,
                                                      float* __restrict__ ne) {
    const int node = blockIdx.x * 4 + (threadIdx.x >> 6);
    if (node >= NN) return;
    const int lane = threadIdx.x & 63;
    const int sub = lane & 7;     // 8-bf16 chunk of the row
    const int eg = lane >> 3;     // edge slot (8)

    const int base = cursor[node];
    const int end  = cursor[node + 1];
    const float dd = dinv[node];

    float acc[8] = {0,0,0,0,0,0,0,0};
    for (int k = base + eg; k < end; k += 8) {
        int s = bucket[k];
        float nrm = dinv[s] * dd;
        short8x hv = *(const short8x*)(hbf + (long long)s * FH + sub * 8);
#pragma unroll
        for (int j = 0; j < 8; ++j)
            acc[j] += bf2f((unsigned short)hv[j]) * nrm;
    }
#pragma unroll
    for (int m = 8; m < 64; m <<= 1) {
#pragma unroll
        for (int j = 0; j < 8; ++j) acc[j] += __shfl_xor(acc[j], m);
    }
    if (eg == 0) {
        short8x hs = *(const short8x*)(hbf + (long long)node * FH + sub * 8);
        float r[8];
#pragma unroll
        for (int j = 0; j < 8; ++j) {
            float v = acc[j] + bf2f((unsigned short)hs[j]) * dd * dd + b_conv[sub * 8 + j];
            r[j] = v >= 0.f ? v : NEG * v;
        }
        float4* o = (float4*)(ne + (long long)node * FH + sub * 8);
        o[0] = make_float4(r[0], r[1], r[2], r[3]);
        o[1] = make_float4(r[4], r[5], r[6], r[7]);
    }
}

// ------------------------- fallback (round-1) path --------------------------

__global__ void detect_kernel(const int* __restrict__ ei32, int* __restrict__ flag) {
    if (blockIdx.x == 0 && threadIdx.x == 0) {
        int ok = 1;
        for (int k = 0; k < 64; ++k)
            if (ei32[2 * k + 1] != 0) { ok = 0; break; }
        *flag = ok;
    }
}

__global__ __launch_bounds__(256) void gemm_kernel(const float* __restrict__ x,
                                                   const float* __restrict__ W,
                                                   float* __restrict__ h) {
    __shared__ float xs[4 * FIN];
    __shared__ float part[4][4][FH];

    const int col = threadIdx.x & 63;
    const int kseg = threadIdx.x >> 6;

    float wreg[64];
#pragma unroll
    for (int kk = 0; kk < 64; ++kk)
        wreg[kk] = W[(kseg * 64 + kk) * FH + col];

    for (int row0 = blockIdx.x * 4; row0 < NN; row0 += gridDim.x * 4) {
        const float4* xv = (const float4*)(x + (long long)row0 * FIN);
        ((float4*)xs)[threadIdx.x] = xv[threadIdx.x];
        __syncthreads();

        float acc[4] = {0.f, 0.f, 0.f, 0.f};
#pragma unroll
        for (int kk = 0; kk < 64; ++kk) {
            const float w = wreg[kk];
            const int k = kseg * 64 + kk;
#pragma unroll
            for (int r = 0; r < 4; ++r)
                acc[r] += xs[r * FIN + k] * w;
        }
#pragma unroll
        for (int r = 0; r < 4; ++r) part[r][kseg][col] = acc[r];
        __syncthreads();

        const int row = threadIdx.x >> 6;
        float s = part[row][0][col] + part[row][1][col] + part[row][2][col] + part[row][3][col];
        h[(long long)(row0 + row) * FH + col] = s;
        __syncthreads();
    }
}

__global__ __launch_bounds__(256) void init_kernel(float* __restrict__ ne,
                                                   float* __restrict__ deg,
                                                   const float* __restrict__ b_conv) {
    int idx = blockIdx.x * 256 + threadIdx.x;
    if (idx < NN * FH) ne[idx] = b_conv[idx & (FH - 1)];
    if (idx < NN) deg[idx] = 1.0f;
}

__global__ __launch_bounds__(256) void deg_kernel(const void* __restrict__ ei,
                                                  float* __restrict__ deg,
                                                  int E, const int* __restrict__ flag) {
    int e = blockIdx.x * 256 + threadIdx.x;
    if (e >= E) return;
    long long d = load_idx(ei, (long long)E + e, *flag);
    atomicAdd(&deg[d], 1.0f);
}

__global__ __launch_bounds__(256) void rsqrt_kernel(float* __restrict__ deg) {
    int i = blockIdx.x * 256 + threadIdx.x;
    if (i < NN) deg[i] = rsqrtf(deg[i]);
}

__global__ __launch_bounds__(256) void selfloop_kernel(const float* __restrict__ h,
                                                       const float* __restrict__ dinv,
                                                       float* __restrict__ ne) {
    int idx = blockIdx.x * 256 + threadIdx.x;
    if (idx >= NN * FH) return;
    int i = idx >> 6;
    float di = dinv[i];
    ne[idx] += h[idx] * di * di;
}

__global__ __launch_bounds__(256) void edge_agg_kernel(const void* __restrict__ ei,
                                                       const float* __restrict__ dinv,
                                                       const float* __restrict__ h,
                                                       float* __restrict__ ne,
                                                       int E, const int* __restrict__ flag) {
    long long t = (long long)blockIdx.x * 256 + threadIdx.x;
    long long e = t >> 4;
    int sub = (int)(t & 15);
    if (e >= E) return;
    int is64 = *flag;
    long long s = load_idx(ei, e, is64);
    long long d = load_idx(ei, (long long)E + e, is64);
    float nrm = dinv[s] * dinv[d];
    float4 hv = *(const float4*)(h + s * FH + sub * 4);
    float* np_ = ne + d * FH + sub * 4;
    atomicAdd(np_ + 0, hv.x * nrm);
    atomicAdd(np_ + 1, hv.y * nrm);
    atomicAdd(np_ + 2, hv.z * nrm);
    atomicAdd(np_ + 3, hv.w * nrm);
}

// ------------------------- MLP head -----------------------------------------
__global__ __launch_bounds__(256) void mlp_kernel(const float* __restrict__ ne,
                                                  const void* __restrict__ idx,
                                                  const float* __restrict__ W1,
                                                  const float* __restrict__ b1,
                                                  const float* __restrict__ W2,
                                                  const float* __restrict__ b2,
                                                  float* __restrict__ out,
                                                  int B, const int* __restrict__ flag,
                                                  int pre_act) {
    const int lane = threadIdx.x & 63;
    const int wid = threadIdx.x >> 6;

    float w1a[16], w1b[16], b1r[16], w2r[16];
#pragma unroll
    for (int o = 0; o < 16; ++o) {
        w1a[o] = W1[lane * 16 + o];
        w1b[o] = W1[(64 + lane) * 16 + o];
        b1r[o] = b1[o];
        w2r[o] = W2[o];
    }
    const float b2v = b2[0];
    const int is64 = *flag;

    for (int pair = blockIdx.x * 4 + wid; pair < B; pair += gridDim.x * 4) {
        long long i0 = load_idx(idx, 2LL * pair, is64);
        long long i1 = load_idx(idx, 2LL * pair + 1, is64);
        float a = ne[i0 * FH + lane];
        float b = ne[i1 * FH + lane];
        if (pre_act) {
            a = a >= 0.f ? a : NEG * a;
            b = b >= 0.f ? b : NEG * b;
        }

        float acc[16];
#pragma unroll
        for (int o = 0; o < 16; ++o) acc[o] = a * w1a[o] + b * w1b[o];
#pragma unroll
        for (int m = 1; m < 64; m <<= 1) {
#pragma unroll
            for (int o = 0; o < 16; ++o) acc[o] += __shfl_xor(acc[o], m, 64);
        }
        if (lane == 0) {
            float s = b2v;
#pragma unroll
            for (int o = 0; o < 16; ++o) {
                float z = acc[o] + b1r[o];
                z = z >= 0.f ? z : NEG * z;
                s += z * w2r[o];
            }
            out[pair] = 1.f / (1.f + expf(-s));
        }
    }
}

extern "C" void kernel_launch(void* const* d_in, const int* in_sizes, int n_in,
                              void* d_out, int out_size, void* d_ws, size_t ws_size,
                              hipStream_t stream) {
    const float* x      = (const float*)d_in[0];
    const void*  ei     = d_in[1];
    const void*  index  = d_in[2];
    const float* W_conv = (const float*)d_in[3];
    const float* b_conv = (const float*)d_in[4];
    const float* W1     = (const float*)d_in[5];
    const float* b1     = (const float*)d_in[6];
    const float* W2     = (const float*)d_in[7];
    const float* b2     = (const float*)d_in[8];
    float* out = (float*)d_out;

    const int E = in_sizes[1] / 2;   // 1.6M
    const int B = in_sizes[2] / 2;   // 16384

    const size_t need_new = (size_t)NN * FH * 2
                          + ((size_t)NN * FH + NN + (NN + 1) + (size_t)E
                             + 1 + NBUCK + (NBUCK + 1) + NBUCK) * 4;

    if (ws_size >= need_new) {
        unsigned short* hbf = (unsigned short*)d_ws;
        float* ne       = (float*)(hbf + (long long)NN * FH);
        float* dinv     = ne + (long long)NN * FH;
        int*   cursor   = (int*)(dinv + NN);          // NN+1 entries
        int*   bucket   = cursor + (NN + 1);
        int*   flag     = bucket + E;
        int*   coarse_cnt    = flag + 1;
        int*   coarse        = coarse_cnt + NBUCK;    // NBUCK+1
        int*   coarse_cursor = coarse + (NBUCK + 1);
        int2*  pairs    = (int2*)ne;                  // staged in dead ne buffer

        detect_zero_kernel<<<1, 256, 0, stream>>>((const int*)ei, flag, coarse_cnt);
        gemm_bf16_kernel<<<(NN + 63) / 64, 256, 0, stream>>>(x, W_conv, hbf);
        coarse_count_kernel<<<256, 256, 0, stream>>>(ei, coarse_cnt, E, flag);
        coarse_scan_kernel<<<1, 256, 0, stream>>>(coarse_cnt, coarse, coarse_cursor);
        part_kernel<<<(E + P1_CH - 1) / P1_CH, 256, 0, stream>>>(ei, coarse_cursor, pairs, E, flag);
        place2_kernel<<<NBUCK, 256, 0, stream>>>(pairs, coarse, cursor, dinv, bucket);
        gather8_kernel<<<(NN + 3) / 4, 256, 0, stream>>>(hbf, dinv, cursor, bucket, b_conv, ne);
        mlp_kernel<<<512, 256, 0, stream>>>(ne, index, W1, b1, W2, b2, out, B, flag, 0);
    } else {
        // fallback: round-1 atomic scatter (fp32)
        float* h   = (float*)d_ws;
        float* ne  = h + (long long)NN * FH;
        float* deg = ne + (long long)NN * FH;
        int* flag  = (int*)(deg + NN);

        detect_kernel<<<1, 64, 0, stream>>>((const int*)ei, flag);
        init_kernel<<<(NN * FH + 255) / 256, 256, 0, stream>>>(ne, deg, b_conv);
        gemm_kernel<<<2048, 256, 0, stream>>>(x, W_conv, h);
        deg_kernel<<<(E + 255) / 256, 256, 0, stream>>>(ei, deg, E, flag);
        rsqrt_kernel<<<(NN + 255) / 256, 256, 0, stream>>>(deg);
        selfloop_kernel<<<(NN * FH + 255) / 256, 256, 0, stream>>>(h, deg, ne);
        edge_agg_kernel<<<(int)(((long long)E * 16 + 255) / 256), 256, 0, stream>>>(ei, deg, h, ne, E, flag);
        mlp_kernel<<<512, 256, 0, stream>>>(ne, index, W1, b1, W2, b2, out, B, flag, 1);
    }
}